// Round 1
// baseline (235.229 us; speedup 1.0000x reference)
//
#include <hip/hip_runtime.h>

#define BATCH 8192
#define IN_DIM 512
#define NT 64
#define NI 31
#define NL 32
#define ODIM 16
#define NPAD (NT*NL)   // 2048 padded GEMM columns

typedef __attribute__((ext_vector_type(8))) short bf16x8;
typedef __attribute__((ext_vector_type(4))) float f32x4;

__device__ __forceinline__ unsigned short f2b(float f) {
  union { float f; unsigned int u; } v; v.f = f;
  unsigned int r = v.u + 0x7fffu + ((v.u >> 16) & 1u);   // RNE
  return (unsigned short)(r >> 16);
}
__device__ __forceinline__ float b2f(unsigned short h) {
  union { unsigned int u; float f; } v; v.u = ((unsigned int)h) << 16;
  return v.f;
}

// ---------------------------------------------------------------------------
// prep: x fp32->bf16 ; W fp32 -> padded [2048][512] bf16 (tree-aligned, 32
// cols/tree, col 31 zero) ; leaf softmax * (1/NT) ; zero d_out for atomics.
// ---------------------------------------------------------------------------
__global__ __launch_bounds__(256) void prep_kernel(
    const float* __restrict__ x, const float* __restrict__ W,
    const float* __restrict__ leafs,
    unsigned short* __restrict__ xb, unsigned short* __restrict__ wb,
    float* __restrict__ lsm, float* __restrict__ out)
{
  const int NX = BATCH*IN_DIM/4;   // 1048576 float4 chunks of x
  const int NW = NPAD*IN_DIM/4;    // 262144 ushort4 chunks of Wpad
  const int NZ = BATCH*ODIM/4;     // 32768 float4 zeros of out
  const int NS = NT*NL;            // 2048 leaf-softmax rows
  int gid = blockIdx.x*256 + threadIdx.x;
  if (gid < NX) {
    float4 v = ((const float4*)x)[gid];
    ushort4 o; o.x=f2b(v.x); o.y=f2b(v.y); o.z=f2b(v.z); o.w=f2b(v.w);
    ((ushort4*)xb)[gid] = o;
  } else if ((gid -= NX) < NW) {
    int c = gid >> 7, ck = gid & 127;      // padded row c, chunk-in-row ck
    int t = c >> 5, i = c & 31;
    ushort4 o;
    if (i == 31) { o.x=0; o.y=0; o.z=0; o.w=0; }
    else {
      float4 v = ((const float4*)(W + (size_t)(t*NI+i)*IN_DIM))[ck];
      o.x=f2b(v.x); o.y=f2b(v.y); o.z=f2b(v.z); o.w=f2b(v.w);
    }
    ((ushort4*)wb)[gid] = o;
  } else if ((gid -= NW) < NZ) {
    float4 z; z.x=0.f; z.y=0.f; z.z=0.f; z.w=0.f;
    ((float4*)out)[gid] = z;
  } else if ((gid -= NZ) < NS) {
    const float* src = leafs + (size_t)gid*ODIM;
    float m = src[0];
    #pragma unroll
    for (int o=1;o<ODIM;++o) m = fmaxf(m, src[o]);
    float e[ODIM]; float s = 0.f;
    #pragma unroll
    for (int o=0;o<ODIM;++o) { e[o] = __expf(src[o]-m); s += e[o]; }
    float inv = 1.f/(s*(float)NT);
    #pragma unroll
    for (int o=0;o<ODIM;++o) lsm[(size_t)gid*ODIM+o] = e[o]*inv;
  }
}

// ---------------------------------------------------------------------------
// fused bf16 GEMM (M=8192,N=2048,K=512) + sigmoid + route products + leaf mix
// tile 128x128, BK=32, 4 waves (2x2 of 64x64), 16x16x32 MFMA.
// ---------------------------------------------------------------------------
__device__ __forceinline__ void async16(const unsigned short* g, unsigned short* l) {
  __builtin_amdgcn_global_load_lds(
      (const __attribute__((address_space(1))) unsigned int*)g,
      (__attribute__((address_space(3))) unsigned int*)l,
      16, 0, 0);
}

__global__ __launch_bounds__(256) void dndf_main(
    const unsigned short* __restrict__ xb, const unsigned short* __restrict__ wb,
    const float* __restrict__ bias, const float* __restrict__ lsm,
    float* __restrict__ out)
{
  // overlay: staging As[128][32] + Bs[128][32] (16 KB)  vs  Pt[128][130] bf16
  __shared__ __align__(16) unsigned short smem[16640];   // 33280 B
  unsigned short* As = smem;
  unsigned short* Bs = smem + 4096;
  unsigned short* Pt = smem;

  const int tid  = threadIdx.x;
  const int lane = tid & 63;
  const int wave = tid >> 6;
  const int wm = wave & 1, wn = wave >> 1;
  const int m0 = blockIdx.x * 128, n0 = blockIdx.y * 128;

  f32x4 acc[4][4];
  #pragma unroll
  for (int i=0;i<4;++i)
    #pragma unroll
    for (int j=0;j<4;++j) { f32x4 z = {0.f,0.f,0.f,0.f}; acc[i][j] = z; }

  // staging: wave handles chunks q = wave*2 + {0,1}; chunk q = rows q*16..+15
  const int srow = lane >> 2, scol = (lane & 3) * 8;
  const int qa = wave*2;
  const unsigned short* ga0 = xb + (size_t)(m0 + qa*16 + srow)*IN_DIM + scol;
  const unsigned short* ga1 = ga0 + 16*IN_DIM;
  const unsigned short* gb0 = wb + (size_t)(n0 + qa*16 + srow)*IN_DIM + scol;
  const unsigned short* gb1 = gb0 + 16*IN_DIM;
  unsigned short* la0 = As + qa*512;   // wave-uniform LDS base, +lane*16B implicit
  unsigned short* la1 = la0 + 512;
  unsigned short* lb0 = Bs + qa*512;
  unsigned short* lb1 = lb0 + 512;

  const int l15 = lane & 15, quad = lane >> 4;
  const int arow = wm*64 + l15;
  const int brow = wn*64 + l15;

  for (int kt = 0; kt < 16; ++kt) {
    const int ko = kt*32;
    async16(ga0 + ko, la0);
    async16(ga1 + ko, la1);
    async16(gb0 + ko, lb0);
    async16(gb1 + ko, lb1);
    __syncthreads();
    bf16x8 af[4], bfr[4];
    #pragma unroll
    for (int mi=0;mi<4;++mi)
      af[mi] = *(const bf16x8*)(As + (arow + mi*16)*32 + quad*8);
    #pragma unroll
    for (int ni=0;ni<4;++ni)
      bfr[ni] = *(const bf16x8*)(Bs + (brow + ni*16)*32 + quad*8);
    #pragma unroll
    for (int mi=0;mi<4;++mi)
      #pragma unroll
      for (int ni=0;ni<4;++ni)
        acc[mi][ni] = __builtin_amdgcn_mfma_f32_16x16x32_bf16(
            af[mi], bfr[ni], acc[mi][ni], 0, 0, 0);
    __syncthreads();
  }

  // --- epilogue 1: bias + sigmoid -> bf16 p-tile in LDS (stride 130 = odd dwords)
  #pragma unroll
  for (int ni=0;ni<4;++ni) {
    int cl = wn*64 + ni*16 + l15;          // local col 0..127
    int gcol = n0 + cl;
    int tt = gcol >> 5, ii = gcol & 31;
    float bv = (ii < NI) ? bias[tt*NI + ii] : 0.f;
    #pragma unroll
    for (int mi=0;mi<4;++mi) {
      #pragma unroll
      for (int r=0;r<4;++r) {
        int lrow = wm*64 + mi*16 + quad*4 + r;       // C/D: row=quad*4+reg
        float v = acc[mi][ni][r] + bv;
        float p = 1.f/(1.f + __expf(-v));
        Pt[lrow*130 + cl] = f2b(p);
      }
    }
  }
  __syncthreads();

  // --- epilogue 2: routes + leaf mix. thread -> (row = tid>>1, 2 of 4 trees)
  const int row = tid >> 1;
  float oacc[ODIM];
  #pragma unroll
  for (int o=0;o<ODIM;++o) oacc[o] = 0.f;

  #pragma unroll
  for (int half=0; half<2; ++half) {
    const int tl = (tid & 1)*2 + half;     // local tree 0..3
    const unsigned short* pr = Pt + row*130 + tl*32;
    float q[31];
    #pragma unroll
    for (int i=0;i<31;++i) q[i] = b2f(pr[i]);
    // hierarchical route expansion: v[j] at level d covers prefix j = l>>(4-d)
    float v[32];
    v[0] = q[0]; v[1] = 1.f - q[0];
    #pragma unroll
    for (int d=1; d<=4; ++d) {
      const int s = 1 << d;
      #pragma unroll
      for (int j=s-1; j>=0; --j) {
        float pj = q[(s-1)+j];
        float base = v[j];
        v[2*j]   = base * pj;          // side 0 -> p
        v[2*j+1] = base * (1.f - pj);  // side 1 -> 1-p
      }
    }
    const float* lp = lsm + (size_t)((n0 >> 5) + tl) * (NL*ODIM);
    #pragma unroll
    for (int l=0;l<NL;++l) {
      float rr = v[l];
      const float4* c4 = (const float4*)(lp + l*ODIM);
      #pragma unroll
      for (int oq=0;oq<4;++oq) {
        float4 c = c4[oq];
        oacc[oq*4+0] += rr*c.x; oacc[oq*4+1] += rr*c.y;
        oacc[oq*4+2] += rr*c.z; oacc[oq*4+3] += rr*c.w;
      }
    }
  }
  // combine tree-pairs across adjacent lanes, then one atomic set per row
  #pragma unroll
  for (int o=0;o<ODIM;++o) oacc[o] += __shfl_xor(oacc[o], 1);
  if ((tid & 1) == 0) {
    float* op = out + (size_t)(m0 + row)*ODIM;
    #pragma unroll
    for (int o=0;o<ODIM;++o) atomicAdd(op + o, oacc[o]);
  }
}

// ---------------------------------------------------------------------------
extern "C" void kernel_launch(void* const* d_in, const int* in_sizes, int n_in,
                              void* d_out, int out_size, void* d_ws, size_t ws_size,
                              hipStream_t stream) {
  const float* x     = (const float*)d_in[0];
  const float* W     = (const float*)d_in[1];
  const float* b     = (const float*)d_in[2];
  const float* leafs = (const float*)d_in[3];
  float* out = (float*)d_out;

  char* ws = (char*)d_ws;
  unsigned short* xb = (unsigned short*)ws;                        // 8,388,608 B
  unsigned short* wb = (unsigned short*)(ws + 8388608);            // 2,097,152 B
  float*          lsm = (float*)(ws + 10485760);                   //   131,072 B

  const int total = BATCH*IN_DIM/4 + NPAD*IN_DIM/4 + BATCH*ODIM/4 + NT*NL; // 1345536
  prep_kernel<<<dim3((total + 255)/256), dim3(256), 0, stream>>>(
      x, W, leafs, xb, wb, lsm, out);
  dndf_main<<<dim3(BATCH/128, NPAD/128), dim3(256), 0, stream>>>(
      xb, wb, b, lsm, out);
}

// Round 2
// 183.016 us; speedup vs baseline: 1.2853x; 1.2853x over previous
//
#include <hip/hip_runtime.h>

#define BATCH 8192
#define IN_DIM 512
#define NT 64
#define NI 31
#define NL 32
#define ODIM 16
#define NPAD (NT*NL)   // 2048 padded GEMM columns
#define NCB 16         // column blocks (2048/128)

typedef __attribute__((ext_vector_type(8))) short bf16x8;
typedef __attribute__((ext_vector_type(4))) float f32x4;

__device__ __forceinline__ unsigned short f2b(float f) {
  union { float f; unsigned int u; } v; v.f = f;
  unsigned int r = v.u + 0x7fffu + ((v.u >> 16) & 1u);   // RNE
  return (unsigned short)(r >> 16);
}
__device__ __forceinline__ float b2f(unsigned short h) {
  union { unsigned int u; float f; } v; v.u = ((unsigned int)h) << 16;
  return v.f;
}

// ---------------------------------------------------------------------------
// prep: x fp32->bf16 ; W fp32 -> padded [2048][512] bf16 (tree-aligned, 32
// cols/tree, col 31 zero) ; leaf softmax * (1/NT).
// ---------------------------------------------------------------------------
__global__ __launch_bounds__(256) void prep_kernel(
    const float* __restrict__ x, const float* __restrict__ W,
    const float* __restrict__ leafs,
    unsigned short* __restrict__ xb, unsigned short* __restrict__ wb,
    float* __restrict__ lsm)
{
  const int NX = BATCH*IN_DIM/4;   // 1048576 float4 chunks of x
  const int NW = NPAD*IN_DIM/4;    // 262144 ushort4 chunks of Wpad
  const int NS = NT*NL;            // 2048 leaf-softmax rows
  int gid = blockIdx.x*256 + threadIdx.x;
  if (gid < NX) {
    float4 v = ((const float4*)x)[gid];
    ushort4 o; o.x=f2b(v.x); o.y=f2b(v.y); o.z=f2b(v.z); o.w=f2b(v.w);
    ((ushort4*)xb)[gid] = o;
  } else if ((gid -= NX) < NW) {
    int c = gid >> 7, ck = gid & 127;      // padded row c, chunk-in-row ck
    int t = c >> 5, i = c & 31;
    ushort4 o;
    if (i == 31) { o.x=0; o.y=0; o.z=0; o.w=0; }
    else {
      float4 v = ((const float4*)(W + (size_t)(t*NI+i)*IN_DIM))[ck];
      o.x=f2b(v.x); o.y=f2b(v.y); o.z=f2b(v.z); o.w=f2b(v.w);
    }
    ((ushort4*)wb)[gid] = o;
  } else if ((gid -= NW) < NS) {
    const float* src = leafs + (size_t)gid*ODIM;
    float m = src[0];
    #pragma unroll
    for (int o=1;o<ODIM;++o) m = fmaxf(m, src[o]);
    float e[ODIM]; float s = 0.f;
    #pragma unroll
    for (int o=0;o<ODIM;++o) { e[o] = __expf(src[o]-m); s += e[o]; }
    float inv = 1.f/(s*(float)NT);
    #pragma unroll
    for (int o=0;o<ODIM;++o) lsm[(size_t)gid*ODIM+o] = e[o]*inv;
  }
}

// ---------------------------------------------------------------------------
// fused bf16 GEMM (M=8192,N=2048,K=512) + sigmoid + route products + leaf mix
// tile 128x128, BK=32, 4 waves (2x2 of 64x64), 16x16x32 MFMA.
// Per-colblock partials go to ws (plain coalesced stores, NO atomics).
// ---------------------------------------------------------------------------
__device__ __forceinline__ void async16(const unsigned short* g, unsigned short* l) {
  __builtin_amdgcn_global_load_lds(
      (const __attribute__((address_space(1))) unsigned int*)g,
      (__attribute__((address_space(3))) unsigned int*)l,
      16, 0, 0);
}

__global__ __launch_bounds__(256) void dndf_main(
    const unsigned short* __restrict__ xb, const unsigned short* __restrict__ wb,
    const float* __restrict__ bias, const float* __restrict__ lsm,
    float* __restrict__ part)
{
  // overlay: staging As[128][32] + Bs[128][32] (16 KB)  vs  Pt[128][130] bf16
  __shared__ __align__(16) unsigned short smem[16640];   // 33280 B
  unsigned short* As = smem;
  unsigned short* Bs = smem + 4096;
  unsigned short* Pt = smem;

  const int tid  = threadIdx.x;
  const int lane = tid & 63;
  const int wave = tid >> 6;
  const int wm = wave & 1, wn = wave >> 1;
  const int m0 = blockIdx.x * 128, n0 = blockIdx.y * 128;

  f32x4 acc[4][4];
  #pragma unroll
  for (int i=0;i<4;++i)
    #pragma unroll
    for (int j=0;j<4;++j) { f32x4 z = {0.f,0.f,0.f,0.f}; acc[i][j] = z; }

  // staging: wave handles chunks q = wave*2 + {0,1}; chunk q = rows q*16..+15
  const int srow = lane >> 2, scol = (lane & 3) * 8;
  const int qa = wave*2;
  const unsigned short* ga0 = xb + (size_t)(m0 + qa*16 + srow)*IN_DIM + scol;
  const unsigned short* ga1 = ga0 + 16*IN_DIM;
  const unsigned short* gb0 = wb + (size_t)(n0 + qa*16 + srow)*IN_DIM + scol;
  const unsigned short* gb1 = gb0 + 16*IN_DIM;
  unsigned short* la0 = As + qa*512;   // wave-uniform LDS base, +lane*16B implicit
  unsigned short* la1 = la0 + 512;
  unsigned short* lb0 = Bs + qa*512;
  unsigned short* lb1 = lb0 + 512;

  const int l15 = lane & 15, quad = lane >> 4;
  const int arow = wm*64 + l15;
  const int brow = wn*64 + l15;

  for (int kt = 0; kt < 16; ++kt) {
    const int ko = kt*32;
    async16(ga0 + ko, la0);
    async16(ga1 + ko, la1);
    async16(gb0 + ko, lb0);
    async16(gb1 + ko, lb1);
    __syncthreads();
    bf16x8 af[4], bfr[4];
    #pragma unroll
    for (int mi=0;mi<4;++mi)
      af[mi] = *(const bf16x8*)(As + (arow + mi*16)*32 + quad*8);
    #pragma unroll
    for (int ni=0;ni<4;++ni)
      bfr[ni] = *(const bf16x8*)(Bs + (brow + ni*16)*32 + quad*8);
    #pragma unroll
    for (int mi=0;mi<4;++mi)
      #pragma unroll
      for (int ni=0;ni<4;++ni)
        acc[mi][ni] = __builtin_amdgcn_mfma_f32_16x16x32_bf16(
            af[mi], bfr[ni], acc[mi][ni], 0, 0, 0);
    __syncthreads();
  }

  // --- epilogue 1: bias + sigmoid -> bf16 p-tile in LDS (stride 130 = odd dwords)
  #pragma unroll
  for (int ni=0;ni<4;++ni) {
    int cl = wn*64 + ni*16 + l15;          // local col 0..127
    int gcol = n0 + cl;
    int tt = gcol >> 5, ii = gcol & 31;
    float bv = (ii < NI) ? bias[tt*NI + ii] : 0.f;
    #pragma unroll
    for (int mi=0;mi<4;++mi) {
      #pragma unroll
      for (int r=0;r<4;++r) {
        int lrow = wm*64 + mi*16 + quad*4 + r;       // C/D: row=quad*4+reg
        float v = acc[mi][ni][r] + bv;
        float p = 1.f/(1.f + __expf(-v));
        Pt[lrow*130 + cl] = f2b(p);
      }
    }
  }
  __syncthreads();

  // --- epilogue 2: routes + leaf mix. thread -> (row = tid>>1, 2 of 4 trees)
  const int row = tid >> 1;
  float oacc[ODIM];
  #pragma unroll
  for (int o=0;o<ODIM;++o) oacc[o] = 0.f;

  #pragma unroll
  for (int half=0; half<2; ++half) {
    const int tl = (tid & 1)*2 + half;     // local tree 0..3
    const unsigned short* pr = Pt + row*130 + tl*32;
    float q[31];
    #pragma unroll
    for (int i=0;i<31;++i) q[i] = b2f(pr[i]);
    // hierarchical route expansion: v[j] at level d covers prefix j = l>>(4-d)
    float v[32];
    v[0] = q[0]; v[1] = 1.f - q[0];
    #pragma unroll
    for (int d=1; d<=4; ++d) {
      const int s = 1 << d;
      #pragma unroll
      for (int j=s-1; j>=0; --j) {
        float pj = q[(s-1)+j];
        float base = v[j];
        v[2*j]   = base * pj;          // side 0 -> p
        v[2*j+1] = base * (1.f - pj);  // side 1 -> 1-p
      }
    }
    const float* lp = lsm + (size_t)((n0 >> 5) + tl) * (NL*ODIM);
    #pragma unroll
    for (int l=0;l<NL;++l) {
      float rr = v[l];
      const float4* c4 = (const float4*)(lp + l*ODIM);
      #pragma unroll
      for (int oq=0;oq<4;++oq) {
        float4 c = c4[oq];
        oacc[oq*4+0] += rr*c.x; oacc[oq*4+1] += rr*c.y;
        oacc[oq*4+2] += rr*c.z; oacc[oq*4+3] += rr*c.w;
      }
    }
  }
  // combine tree-pairs across adjacent lanes, then one plain store per row
  #pragma unroll
  for (int o=0;o<ODIM;++o) oacc[o] += __shfl_xor(oacc[o], 1);
  if ((tid & 1) == 0) {
    // partial layout: part[colblock][row][16] fp32, fully coalesced
    float* op = part + ((size_t)blockIdx.y*BATCH + (m0 + row))*ODIM;
    float4* op4 = (float4*)op;
    #pragma unroll
    for (int oq=0;oq<4;++oq) {
      float4 v; v.x=oacc[oq*4+0]; v.y=oacc[oq*4+1];
      v.z=oacc[oq*4+2]; v.w=oacc[oq*4+3];
      op4[oq] = v;
    }
  }
}

// ---------------------------------------------------------------------------
// reduce: out[row][o] = sum over 16 colblock partials
// ---------------------------------------------------------------------------
__global__ __launch_bounds__(256) void reduce_kernel(
    const float* __restrict__ part, float* __restrict__ out)
{
  int gid = blockIdx.x*256 + threadIdx.x;   // 32768 float4 tasks
  const float4* p4 = (const float4*)part;
  float4 s = p4[gid];
  #pragma unroll
  for (int cb=1; cb<NCB; ++cb) {
    float4 v = p4[(size_t)cb*(BATCH*ODIM/4) + gid];
    s.x+=v.x; s.y+=v.y; s.z+=v.z; s.w+=v.w;
  }
  ((float4*)out)[gid] = s;
}

// ---------------------------------------------------------------------------
extern "C" void kernel_launch(void* const* d_in, const int* in_sizes, int n_in,
                              void* d_out, int out_size, void* d_ws, size_t ws_size,
                              hipStream_t stream) {
  const float* x     = (const float*)d_in[0];
  const float* W     = (const float*)d_in[1];
  const float* b     = (const float*)d_in[2];
  const float* leafs = (const float*)d_in[3];
  float* out = (float*)d_out;

  char* ws = (char*)d_ws;
  unsigned short* xb  = (unsigned short*)ws;                       // 8,388,608 B
  unsigned short* wb  = (unsigned short*)(ws + 8388608);           // 2,097,152 B
  float*          lsm = (float*)(ws + 10485760);                   //   131,072 B
  float*          part= (float*)(ws + 10616832);                   // 8,388,608 B partials

  const int total = BATCH*IN_DIM/4 + NPAD*IN_DIM/4 + NT*NL;        // 1312768
  prep_kernel<<<dim3((total + 255)/256), dim3(256), 0, stream>>>(
      x, W, leafs, xb, wb, lsm);
  dndf_main<<<dim3(BATCH/128, NPAD/128), dim3(256), 0, stream>>>(
      xb, wb, b, lsm, part);
  reduce_kernel<<<dim3(BATCH*ODIM/4/256), dim3(256), 0, stream>>>(part, out);
}

// Round 3
// 161.966 us; speedup vs baseline: 1.4523x; 1.1300x over previous
//
#include <hip/hip_runtime.h>

#define BATCH 8192
#define IN_DIM 512
#define NT 64
#define NI 31
#define NL 32
#define ODIM 16
#define NPAD (NT*NL)   // 2048 padded GEMM columns
#define NCB 16         // column blocks (2048/128)

typedef __attribute__((ext_vector_type(8))) short bf16x8;
typedef __attribute__((ext_vector_type(4))) float f32x4;

__device__ __forceinline__ unsigned short f2b(float f) {
  union { float f; unsigned int u; } v; v.f = f;
  unsigned int r = v.u + 0x7fffu + ((v.u >> 16) & 1u);   // RNE
  return (unsigned short)(r >> 16);
}
__device__ __forceinline__ float b2f(unsigned short h) {
  union { unsigned int u; float f; } v; v.u = ((unsigned int)h) << 16;
  return v.f;
}

// ---------------------------------------------------------------------------
// prep: x fp32->bf16 ; W fp32 -> padded [2048][512] bf16 (tree-aligned, 32
// cols/tree, col 31 zero) ; leaf softmax * (1/NT).
// ---------------------------------------------------------------------------
__global__ __launch_bounds__(256) void prep_kernel(
    const float* __restrict__ x, const float* __restrict__ W,
    const float* __restrict__ leafs,
    unsigned short* __restrict__ xb, unsigned short* __restrict__ wb,
    float* __restrict__ lsm)
{
  const int NX = BATCH*IN_DIM/4;   // 1048576 float4 chunks of x
  const int NW = NPAD*IN_DIM/4;    // 262144 ushort4 chunks of Wpad
  const int NS = NT*NL;            // 2048 leaf-softmax rows
  int gid = blockIdx.x*256 + threadIdx.x;
  if (gid < NX) {
    float4 v = ((const float4*)x)[gid];
    ushort4 o; o.x=f2b(v.x); o.y=f2b(v.y); o.z=f2b(v.z); o.w=f2b(v.w);
    ((ushort4*)xb)[gid] = o;
  } else if ((gid -= NX) < NW) {
    int c = gid >> 7, ck = gid & 127;      // padded row c, chunk-in-row ck
    int t = c >> 5, i = c & 31;
    ushort4 o;
    if (i == 31) { o.x=0; o.y=0; o.z=0; o.w=0; }
    else {
      float4 v = ((const float4*)(W + (size_t)(t*NI+i)*IN_DIM))[ck];
      o.x=f2b(v.x); o.y=f2b(v.y); o.z=f2b(v.z); o.w=f2b(v.w);
    }
    ((ushort4*)wb)[gid] = o;
  } else if ((gid -= NW) < NS) {
    const float* src = leafs + (size_t)gid*ODIM;
    float m = src[0];
    #pragma unroll
    for (int o=1;o<ODIM;++o) m = fmaxf(m, src[o]);
    float e[ODIM]; float s = 0.f;
    #pragma unroll
    for (int o=0;o<ODIM;++o) { e[o] = __expf(src[o]-m); s += e[o]; }
    float inv = 1.f/(s*(float)NT);
    #pragma unroll
    for (int o=0;o<ODIM;++o) lsm[(size_t)gid*ODIM+o] = e[o]*inv;
  }
}

// ---------------------------------------------------------------------------
// fused bf16 GEMM (M=8192,N=2048,K=512) + sigmoid + route products + leaf mix
// tile 128x128, BK=32, 4 waves (2x2 of 64x64), 16x16x32 MFMA.
// DOUBLE-BUFFERED global_load_lds prefetch: tile kt+1 issued right after the
// barrier that drains tile kt, so the next barrier's vmcnt(0) drain sees a
// load that has been in flight for a full compute phase.
// ---------------------------------------------------------------------------
__device__ __forceinline__ void async16(const unsigned short* g, unsigned short* l) {
  __builtin_amdgcn_global_load_lds(
      (const __attribute__((address_space(1))) unsigned int*)g,
      (__attribute__((address_space(3))) unsigned int*)l,
      16, 0, 0);
}

__global__ __launch_bounds__(256, 4) void dndf_main(
    const unsigned short* __restrict__ xb, const unsigned short* __restrict__ wb,
    const float* __restrict__ bias, const float* __restrict__ lsm,
    float* __restrict__ part)
{
  // staging: buf0 As[0..4095] Bs[4096..8191]; buf1 As[8192..] Bs[12288..]
  // epilogue overlay Pt[128][130] bf16 = 16640 shorts
  __shared__ __align__(16) unsigned short smem[16640];   // 33280 B
  unsigned short* Pt = smem;

  const int tid  = threadIdx.x;
  const int lane = tid & 63;
  const int wave = tid >> 6;
  const int wm = wave & 1, wn = wave >> 1;
  const int m0 = blockIdx.x * 128, n0 = blockIdx.y * 128;

  f32x4 acc[4][4];
  #pragma unroll
  for (int i=0;i<4;++i)
    #pragma unroll
    for (int j=0;j<4;++j) { f32x4 z = {0.f,0.f,0.f,0.f}; acc[i][j] = z; }

  // staging: wave handles chunks q = wave*2 + {0,1}; chunk q = rows q*16..+15
  const int srow = lane >> 2, scol = (lane & 3) * 8;
  const int qa = wave*2;
  const unsigned short* ga0 = xb + (size_t)(m0 + qa*16 + srow)*IN_DIM + scol;
  const unsigned short* ga1 = ga0 + 16*IN_DIM;
  const unsigned short* gb0 = wb + (size_t)(n0 + qa*16 + srow)*IN_DIM + scol;
  const unsigned short* gb1 = gb0 + 16*IN_DIM;
  unsigned short* la0 = smem + qa*512;   // buf0 A; wave-uniform base
  unsigned short* lb0 = smem + 4096 + qa*512;

  const int l15 = lane & 15, quad = lane >> 4;
  const int arow = wm*64 + l15;
  const int brow = wn*64 + l15;

  // prologue: tile 0 into buf0
  async16(ga0, la0);
  async16(ga0 + 16*IN_DIM, la0 + 512);
  async16(gb0, lb0);
  async16(gb0 + 16*IN_DIM, lb0 + 512);

  for (int kt = 0; kt < 16; ++kt) {
    __syncthreads();                       // drains tile-kt loads (vmcnt 0)
    const int cur = (kt & 1) * 8192;
    if (kt < 15) {                         // prefetch kt+1 into other buffer
      const int nxt = ((kt + 1) & 1) * 8192;
      const int ko = (kt + 1) * 32;
      async16(ga0 + ko, smem + nxt + qa*512);
      async16(ga1 + ko, smem + nxt + qa*512 + 512);
      async16(gb0 + ko, smem + nxt + 4096 + qa*512);
      async16(gb1 + ko, smem + nxt + 4096 + qa*512 + 512);
    }
    const unsigned short* As = smem + cur;
    const unsigned short* Bs = smem + cur + 4096;
    bf16x8 af[4], bfr[4];
    #pragma unroll
    for (int mi=0;mi<4;++mi)
      af[mi] = *(const bf16x8*)(As + (arow + mi*16)*32 + quad*8);
    #pragma unroll
    for (int ni=0;ni<4;++ni)
      bfr[ni] = *(const bf16x8*)(Bs + (brow + ni*16)*32 + quad*8);
    #pragma unroll
    for (int mi=0;mi<4;++mi)
      #pragma unroll
      for (int ni=0;ni<4;++ni)
        acc[mi][ni] = __builtin_amdgcn_mfma_f32_16x16x32_bf16(
            af[mi], bfr[ni], acc[mi][ni], 0, 0, 0);
  }
  __syncthreads();   // all ds_reads done before Pt overlays staging

  // --- epilogue 1: bias + sigmoid -> bf16 p-tile in LDS (stride 130 = odd dwords)
  #pragma unroll
  for (int ni=0;ni<4;++ni) {
    int cl = wn*64 + ni*16 + l15;          // local col 0..127
    int gcol = n0 + cl;
    int tt = gcol >> 5, ii = gcol & 31;
    float bv = (ii < NI) ? bias[tt*NI + ii] : 0.f;
    #pragma unroll
    for (int mi=0;mi<4;++mi) {
      #pragma unroll
      for (int r=0;r<4;++r) {
        int lrow = wm*64 + mi*16 + quad*4 + r;       // C/D: row=quad*4+reg
        float v = acc[mi][ni][r] + bv;
        float p = 1.f/(1.f + __expf(-v));
        Pt[lrow*130 + cl] = f2b(p);
      }
    }
  }
  __syncthreads();

  // --- epilogue 2: routes + leaf mix. thread -> (row = tid>>1, 2 of 4 trees)
  const int row = tid >> 1;
  float oacc[ODIM];
  #pragma unroll
  for (int o=0;o<ODIM;++o) oacc[o] = 0.f;

  #pragma unroll
  for (int half=0; half<2; ++half) {
    const int tl = (tid & 1)*2 + half;     // local tree 0..3
    const unsigned short* pr = Pt + row*130 + tl*32;
    // hierarchical route expansion, reading node probs from LDS at use site
    float v[32];
    float p0 = b2f(pr[0]);
    v[0] = p0; v[1] = 1.f - p0;
    #pragma unroll
    for (int d=1; d<=4; ++d) {
      const int s = 1 << d;
      #pragma unroll
      for (int j=s-1; j>=0; --j) {
        float pj = b2f(pr[(s-1)+j]);
        float base = v[j];
        v[2*j]   = base * pj;          // side 0 -> p
        v[2*j+1] = base * (1.f - pj);  // side 1 -> 1-p
      }
    }
    const float* lp = lsm + (size_t)((n0 >> 5) + tl) * (NL*ODIM);
    #pragma unroll
    for (int l=0;l<NL;++l) {
      float rr = v[l];
      const float4* c4 = (const float4*)(lp + l*ODIM);
      #pragma unroll
      for (int oq=0;oq<4;++oq) {
        float4 c = c4[oq];
        oacc[oq*4+0] += rr*c.x; oacc[oq*4+1] += rr*c.y;
        oacc[oq*4+2] += rr*c.z; oacc[oq*4+3] += rr*c.w;
      }
    }
  }
  // combine tree-pairs across adjacent lanes, then one plain store per row
  #pragma unroll
  for (int o=0;o<ODIM;++o) oacc[o] += __shfl_xor(oacc[o], 1);
  if ((tid & 1) == 0) {
    // partial layout: part[colblock][row][16] fp32, fully coalesced
    float* op = part + ((size_t)blockIdx.y*BATCH + (m0 + row))*ODIM;
    float4* op4 = (float4*)op;
    #pragma unroll
    for (int oq=0;oq<4;++oq) {
      float4 v; v.x=oacc[oq*4+0]; v.y=oacc[oq*4+1];
      v.z=oacc[oq*4+2]; v.w=oacc[oq*4+3];
      op4[oq] = v;
    }
  }
}

// ---------------------------------------------------------------------------
// reduce: out[row][o] = sum over 16 colblock partials
// ---------------------------------------------------------------------------
__global__ __launch_bounds__(256) void reduce_kernel(
    const float* __restrict__ part, float* __restrict__ out)
{
  int gid = blockIdx.x*256 + threadIdx.x;   // 32768 float4 tasks
  const float4* p4 = (const float4*)part;
  float4 s = p4[gid];
  #pragma unroll
  for (int cb=1; cb<NCB; ++cb) {
    float4 v = p4[(size_t)cb*(BATCH*ODIM/4) + gid];
    s.x+=v.x; s.y+=v.y; s.z+=v.z; s.w+=v.w;
  }
  ((float4*)out)[gid] = s;
}

// ---------------------------------------------------------------------------
extern "C" void kernel_launch(void* const* d_in, const int* in_sizes, int n_in,
                              void* d_out, int out_size, void* d_ws, size_t ws_size,
                              hipStream_t stream) {
  const float* x     = (const float*)d_in[0];
  const float* W     = (const float*)d_in[1];
  const float* b     = (const float*)d_in[2];
  const float* leafs = (const float*)d_in[3];
  float* out = (float*)d_out;

  char* ws = (char*)d_ws;
  unsigned short* xb  = (unsigned short*)ws;                       // 8,388,608 B
  unsigned short* wb  = (unsigned short*)(ws + 8388608);           // 2,097,152 B
  float*          lsm = (float*)(ws + 10485760);                   //   131,072 B
  float*          part= (float*)(ws + 10616832);                   // 8,388,608 B partials

  const int total = BATCH*IN_DIM/4 + NPAD*IN_DIM/4 + NT*NL;        // 1312768
  prep_kernel<<<dim3((total + 255)/256), dim3(256), 0, stream>>>(
      x, W, leafs, xb, wb, lsm);
  dndf_main<<<dim3(BATCH/128, NPAD/128), dim3(256), 0, stream>>>(
      xb, wb, b, lsm, part);
  reduce_kernel<<<dim3(BATCH*ODIM/4/256), dim3(256), 0, stream>>>(part, out);
}

// Round 4
// 139.550 us; speedup vs baseline: 1.6856x; 1.1606x over previous
//
#include <hip/hip_runtime.h>

#define BATCH 8192
#define IN_DIM 512
#define NT 64
#define NI 31
#define NL 32
#define ODIM 16
#define NPAD (NT*NL)   // 2048 padded GEMM columns

typedef __attribute__((ext_vector_type(8))) short bf16x8;
typedef __attribute__((ext_vector_type(4))) float f32x4;

__device__ __forceinline__ unsigned short f2b(float f) {
  union { float f; unsigned int u; } v; v.f = f;
  unsigned int r = v.u + 0x7fffu + ((v.u >> 16) & 1u);   // RNE
  return (unsigned short)(r >> 16);
}
__device__ __forceinline__ float b2f(unsigned short h) {
  union { unsigned int u; float f; } v; v.u = ((unsigned int)h) << 16;
  return v.f;
}

// ---------------------------------------------------------------------------
// prep: x fp32->bf16 ; W fp32 -> padded [2048][512] bf16 (tree-aligned, 32
// cols/tree, col 31 zero) ; leaf softmax * (1/NT).
// ---------------------------------------------------------------------------
__global__ __launch_bounds__(256) void prep_kernel(
    const float* __restrict__ x, const float* __restrict__ W,
    const float* __restrict__ leafs,
    unsigned short* __restrict__ xb, unsigned short* __restrict__ wb,
    float* __restrict__ lsm)
{
  const int NX = BATCH*IN_DIM/4;   // 1048576 float4 chunks of x
  const int NW = NPAD*IN_DIM/4;    // 262144 ushort4 chunks of Wpad
  const int NS = NT*NL;            // 2048 leaf-softmax rows
  int gid = blockIdx.x*256 + threadIdx.x;
  if (gid < NX) {
    float4 v = ((const float4*)x)[gid];
    ushort4 o; o.x=f2b(v.x); o.y=f2b(v.y); o.z=f2b(v.z); o.w=f2b(v.w);
    ((ushort4*)xb)[gid] = o;
  } else if ((gid -= NX) < NW) {
    int c = gid >> 7, ck = gid & 127;      // padded row c, chunk-in-row ck
    int t = c >> 5, i = c & 31;
    ushort4 o;
    if (i == 31) { o.x=0; o.y=0; o.z=0; o.w=0; }
    else {
      float4 v = ((const float4*)(W + (size_t)(t*NI+i)*IN_DIM))[ck];
      o.x=f2b(v.x); o.y=f2b(v.y); o.z=f2b(v.z); o.w=f2b(v.w);
    }
    ((ushort4*)wb)[gid] = o;
  } else if ((gid -= NW) < NS) {
    const float* src = leafs + (size_t)gid*ODIM;
    float m = src[0];
    #pragma unroll
    for (int o=1;o<ODIM;++o) m = fmaxf(m, src[o]);
    float e[ODIM]; float s = 0.f;
    #pragma unroll
    for (int o=0;o<ODIM;++o) { e[o] = __expf(src[o]-m); s += e[o]; }
    float inv = 1.f/(s*(float)NT);
    #pragma unroll
    for (int o=0;o<ODIM;++o) lsm[(size_t)gid*ODIM+o] = e[o]*inv;
  }
}

// ---------------------------------------------------------------------------
// gemm: bf16 GEMM (M=8192,N=2048,K=512), 128x128 tile, BK=32, dbuf prefetch.
// Epilogue: bias + sigmoid, store p TRANSPOSED p_t[col][row] bf16 (ushort4 of
// 4 consecutive M-rows per lane; C/D frag rows quad*4+r are M-consecutive).
// No Pt LDS, no route work -> low register pressure, no spill at (256,4).
// ---------------------------------------------------------------------------
__device__ __forceinline__ void async16(const unsigned short* g, unsigned short* l) {
  __builtin_amdgcn_global_load_lds(
      (const __attribute__((address_space(1))) unsigned int*)g,
      (__attribute__((address_space(3))) unsigned int*)l,
      16, 0, 0);
}

__global__ __launch_bounds__(256, 4) void gemm_kernel(
    const unsigned short* __restrict__ xb, const unsigned short* __restrict__ wb,
    const float* __restrict__ bias, unsigned short* __restrict__ pt)
{
  // dbuf staging only: buf k at (k&1)*8192; A shorts [0,4096), B [4096,8192)
  __shared__ __align__(16) unsigned short smem[16384];   // 32768 B

  const int tid  = threadIdx.x;
  const int lane = tid & 63;
  const int wave = tid >> 6;
  const int wm = wave & 1, wn = wave >> 1;
  const int m0 = blockIdx.x * 128, n0 = blockIdx.y * 128;

  f32x4 acc[4][4];
  #pragma unroll
  for (int i=0;i<4;++i)
    #pragma unroll
    for (int j=0;j<4;++j) { f32x4 z = {0.f,0.f,0.f,0.f}; acc[i][j] = z; }

  const int srow = lane >> 2, scol = (lane & 3) * 8;
  const int qa = wave*2;
  const unsigned short* ga0 = xb + (size_t)(m0 + qa*16 + srow)*IN_DIM + scol;
  const unsigned short* ga1 = ga0 + 16*IN_DIM;
  const unsigned short* gb0 = wb + (size_t)(n0 + qa*16 + srow)*IN_DIM + scol;
  const unsigned short* gb1 = gb0 + 16*IN_DIM;

  const int l15 = lane & 15, quad = lane >> 4;
  const int arow = wm*64 + l15;
  const int brow = wn*64 + l15;

  // prologue: tile 0 into buf0
  async16(ga0, smem + qa*512);
  async16(ga1, smem + qa*512 + 512);
  async16(gb0, smem + 4096 + qa*512);
  async16(gb1, smem + 4096 + qa*512 + 512);

  for (int kt = 0; kt < 16; ++kt) {
    __syncthreads();                       // drains tile-kt loads
    const int cur = (kt & 1) * 8192;
    if (kt < 15) {                         // prefetch kt+1 into other buffer
      const int nxt = ((kt + 1) & 1) * 8192;
      const int ko = (kt + 1) * 32;
      async16(ga0 + ko, smem + nxt + qa*512);
      async16(ga1 + ko, smem + nxt + qa*512 + 512);
      async16(gb0 + ko, smem + nxt + 4096 + qa*512);
      async16(gb1 + ko, smem + nxt + 4096 + qa*512 + 512);
    }
    const unsigned short* As = smem + cur;
    const unsigned short* Bs = smem + cur + 4096;
    bf16x8 af[4], bfr[4];
    #pragma unroll
    for (int mi=0;mi<4;++mi)
      af[mi] = *(const bf16x8*)(As + (arow + mi*16)*32 + quad*8);
    #pragma unroll
    for (int ni=0;ni<4;++ni)
      bfr[ni] = *(const bf16x8*)(Bs + (brow + ni*16)*32 + quad*8);
    #pragma unroll
    for (int mi=0;mi<4;++mi)
      #pragma unroll
      for (int ni=0;ni<4;++ni)
        acc[mi][ni] = __builtin_amdgcn_mfma_f32_16x16x32_bf16(
            af[mi], bfr[ni], acc[mi][ni], 0, 0, 0);
  }

  // epilogue: bias + sigmoid -> p_t[gcol][grow..grow+3] as one ushort4
  #pragma unroll
  for (int ni=0;ni<4;++ni) {
    int gcol = n0 + wn*64 + ni*16 + l15;
    int tt = gcol >> 5, ii = gcol & 31;
    float bv = (ii < NI) ? bias[tt*NI + ii] : 0.f;
    #pragma unroll
    for (int mi=0;mi<4;++mi) {
      ushort4 s4;
      float v0 = acc[mi][ni][0] + bv, v1 = acc[mi][ni][1] + bv;
      float v2 = acc[mi][ni][2] + bv, v3 = acc[mi][ni][3] + bv;
      s4.x = f2b(1.f/(1.f + __expf(-v0)));
      s4.y = f2b(1.f/(1.f + __expf(-v1)));
      s4.z = f2b(1.f/(1.f + __expf(-v2)));
      s4.w = f2b(1.f/(1.f + __expf(-v3)));
      *(ushort4*)(pt + (size_t)gcol*BATCH + (m0 + wm*64 + mi*16 + quad*4)) = s4;
    }
  }
}

// ---------------------------------------------------------------------------
// route: per block 16 rows x all 64 trees. Wave w -> trees [w*16, w*16+16);
// lane: row = r0 + (lane&15), tree-subgroup (lane>>4) covers 4 trees serially.
// p_t reads are lane-coalesced (consecutive rows = consecutive shorts).
// Tree reduce: shfl_xor(16,32) within wave, LDS across the 4 waves, store out.
// ---------------------------------------------------------------------------
__global__ __launch_bounds__(256) void route_kernel(
    const unsigned short* __restrict__ pt, const float* __restrict__ lsm,
    float* __restrict__ out)
{
  __shared__ float red[4][16][ODIM];   // 4 KB
  const int tid  = threadIdx.x;
  const int wave = tid >> 6, lane = tid & 63;
  const int r0   = blockIdx.x * 16;
  const int rloc = lane & 15;
  const int row  = r0 + rloc;
  const int tgrp = lane >> 4;

  float oacc[ODIM];
  #pragma unroll
  for (int o=0;o<ODIM;++o) oacc[o] = 0.f;

  #pragma unroll
  for (int j=0;j<4;++j) {
    const int t = wave*16 + tgrp*4 + j;
    const unsigned short* pp = pt + (size_t)t*NL*BATCH + row;
    // hierarchical route expansion; internal i lives at pp[i*BATCH]
    float v[32];
    float p0 = b2f(pp[0]);
    v[0] = p0; v[1] = 1.f - p0;
    #pragma unroll
    for (int d=1; d<=4; ++d) {
      const int s = 1 << d;
      #pragma unroll
      for (int jj=s-1; jj>=0; --jj) {
        float pj = b2f(pp[(size_t)((s-1)+jj)*BATCH]);
        float base = v[jj];
        v[2*jj]   = base * pj;
        v[2*jj+1] = base * (1.f - pj);
      }
    }
    const float* lp = lsm + (size_t)t*NL*ODIM;
    #pragma unroll
    for (int l=0;l<NL;++l) {
      float rr = v[l];
      const float4* c4 = (const float4*)(lp + l*ODIM);
      #pragma unroll
      for (int oq=0;oq<4;++oq) {
        float4 c = c4[oq];
        oacc[oq*4+0] += rr*c.x; oacc[oq*4+1] += rr*c.y;
        oacc[oq*4+2] += rr*c.z; oacc[oq*4+3] += rr*c.w;
      }
    }
  }
  // combine the 4 tree-subgroups holding the same row
  #pragma unroll
  for (int o=0;o<ODIM;++o) {
    oacc[o] += __shfl_xor(oacc[o], 16);
    oacc[o] += __shfl_xor(oacc[o], 32);
  }
  if (tgrp == 0) {
    #pragma unroll
    for (int o=0;o<ODIM;++o) red[wave][rloc][o] = oacc[o];
  }
  __syncthreads();
  if (tid < 64) {
    int r = tid >> 2, oq = tid & 3;
    float4 s = *(const float4*)&red[0][r][oq*4];
    #pragma unroll
    for (int w=1;w<4;++w) {
      float4 v = *(const float4*)&red[w][r][oq*4];
      s.x+=v.x; s.y+=v.y; s.z+=v.z; s.w+=v.w;
    }
    *(float4*)(out + (size_t)(r0+r)*ODIM + oq*4) = s;
  }
}

// ---------------------------------------------------------------------------
extern "C" void kernel_launch(void* const* d_in, const int* in_sizes, int n_in,
                              void* d_out, int out_size, void* d_ws, size_t ws_size,
                              hipStream_t stream) {
  const float* x     = (const float*)d_in[0];
  const float* W     = (const float*)d_in[1];
  const float* b     = (const float*)d_in[2];
  const float* leafs = (const float*)d_in[3];
  float* out = (float*)d_out;

  char* ws = (char*)d_ws;
  unsigned short* xb  = (unsigned short*)ws;                       // 8,388,608 B
  unsigned short* wb  = (unsigned short*)(ws + 8388608);           // 2,097,152 B
  float*          lsm = (float*)(ws + 10485760);                   //   131,072 B
  unsigned short* pt  = (unsigned short*)(ws + 10616832);          // 33,554,432 B p_t[2048][8192]

  const int total = BATCH*IN_DIM/4 + NPAD*IN_DIM/4 + NT*NL;        // 1312768
  prep_kernel<<<dim3((total + 255)/256), dim3(256), 0, stream>>>(
      x, W, leafs, xb, wb, lsm);
  gemm_kernel<<<dim3(BATCH/128, NPAD/128), dim3(256), 0, stream>>>(
      xb, wb, b, pt);
  route_kernel<<<dim3(BATCH/16), dim3(256), 0, stream>>>(pt, lsm, out);
}

// Round 5
// 139.499 us; speedup vs baseline: 1.6862x; 1.0004x over previous
//
#include <hip/hip_runtime.h>

#define BATCH 8192
#define IN_DIM 512
#define NT 64
#define NI 31
#define NL 32
#define ODIM 16
#define NPAD (NT*NL)   // 2048 padded GEMM columns
#define NTB 8          // tree-blocks in route split
#define TPB 8          // trees per route block

typedef __attribute__((ext_vector_type(8))) short bf16x8;
typedef __attribute__((ext_vector_type(4))) float f32x4;

__device__ __forceinline__ unsigned short f2b(float f) {
  union { float f; unsigned int u; } v; v.f = f;
  unsigned int r = v.u + 0x7fffu + ((v.u >> 16) & 1u);   // RNE
  return (unsigned short)(r >> 16);
}
__device__ __forceinline__ float b2f(unsigned short h) {
  union { unsigned int u; float f; } v; v.u = ((unsigned int)h) << 16;
  return v.f;
}

// ---------------------------------------------------------------------------
// prep: x,W fp32 -> bf16 with 16B-granule XOR swizzle (slot g of each 32-K
// window holds source granule g ^ ((row>>1)&3)) so the GEMM's LDS reads are
// bank-conflict-free; W padded to 32 cols/tree; leaf softmax * (1/NT).
// ---------------------------------------------------------------------------
__global__ __launch_bounds__(256) void prep_kernel(
    const float* __restrict__ x, const float* __restrict__ W,
    const float* __restrict__ leafs,
    unsigned short* __restrict__ xb, unsigned short* __restrict__ wb,
    float* __restrict__ lsm)
{
  const int NXg = BATCH * (IN_DIM/8);   // 524288 granules of 8
  const int NWg = NPAD  * (IN_DIM/8);   // 131072 granules
  const int NS  = NT*NL;                // 2048 leaf rows
  int gid = blockIdx.x*256 + threadIdx.x;
  if (gid < NXg) {
    int row = gid >> 6, k8 = gid & 63;
    int kt = k8 >> 2, g = k8 & 3;
    int gs = g ^ ((row >> 1) & 3);
    const float* s = x + (size_t)row*IN_DIM + kt*32 + gs*8;
    float4 v0 = ((const float4*)s)[0], v1 = ((const float4*)s)[1];
    ushort4 o0, o1;
    o0.x=f2b(v0.x); o0.y=f2b(v0.y); o0.z=f2b(v0.z); o0.w=f2b(v0.w);
    o1.x=f2b(v1.x); o1.y=f2b(v1.y); o1.z=f2b(v1.z); o1.w=f2b(v1.w);
    ((ushort4*)xb)[gid*2]   = o0;
    ((ushort4*)xb)[gid*2+1] = o1;
  } else if ((gid -= NXg) < NWg) {
    int row = gid >> 6, k8 = gid & 63;
    int t = row >> 5, i = row & 31;
    int kt = k8 >> 2, g = k8 & 3;
    int gs = g ^ ((row >> 1) & 3);
    ushort4 o0, o1;
    if (i == 31) { o0.x=o0.y=o0.z=o0.w=0; o1=o0; }
    else {
      const float* s = W + (size_t)(t*NI+i)*IN_DIM + kt*32 + gs*8;
      float4 v0 = ((const float4*)s)[0], v1 = ((const float4*)s)[1];
      o0.x=f2b(v0.x); o0.y=f2b(v0.y); o0.z=f2b(v0.z); o0.w=f2b(v0.w);
      o1.x=f2b(v1.x); o1.y=f2b(v1.y); o1.z=f2b(v1.z); o1.w=f2b(v1.w);
    }
    ((ushort4*)wb)[gid*2]   = o0;
    ((ushort4*)wb)[gid*2+1] = o1;
  } else if ((gid -= NWg) < NS) {
    const float* src = leafs + (size_t)gid*ODIM;
    float m = src[0];
    #pragma unroll
    for (int o=1;o<ODIM;++o) m = fmaxf(m, src[o]);
    float e[ODIM]; float s = 0.f;
    #pragma unroll
    for (int o=0;o<ODIM;++o) { e[o] = __expf(src[o]-m); s += e[o]; }
    float inv = 1.f/(s*(float)NT);
    #pragma unroll
    for (int o=0;o<ODIM;++o) lsm[(size_t)gid*ODIM+o] = e[o]*inv;
  }
}

// ---------------------------------------------------------------------------
// gemm: bf16 (M=8192,N=2048,K=512), 128x128 tile, BK=32, 3-stage pipeline
// with raw s_barrier + manual vmcnt(N) (AITER-style; never vmcnt(0) except
// the peeled last tile). Swizzled LDS reads (conflict-free). Epilogue:
// bias+sigmoid, transposed scatter store into pt[col][row] bf16.
// ---------------------------------------------------------------------------
__device__ __forceinline__ void async16(const unsigned short* g, unsigned short* l) {
  __builtin_amdgcn_global_load_lds(
      (const __attribute__((address_space(1))) unsigned int*)g,
      (__attribute__((address_space(3))) unsigned int*)l,
      16, 0, 0);
}

__global__ __launch_bounds__(256, 3) void gemm_kernel(
    const unsigned short* __restrict__ xb, const unsigned short* __restrict__ wb,
    const float* __restrict__ bias, unsigned short* __restrict__ pt)
{
  // 3 staging buffers: buf b at b*8192 shorts; A at +0 (4096), B at +4096
  __shared__ __align__(16) unsigned short smem[24576];   // 49152 B

  const int tid  = threadIdx.x;
  const int lane = tid & 63;
  const int wave = tid >> 6;
  const int wm = wave & 1, wn = wave >> 1;
  const int m0 = blockIdx.x * 128, n0 = blockIdx.y * 128;

  f32x4 acc[4][4];
  #pragma unroll
  for (int i=0;i<4;++i)
    #pragma unroll
    for (int j=0;j<4;++j) { f32x4 z = {0.f,0.f,0.f,0.f}; acc[i][j] = z; }

  const int srow = lane >> 2, scol = (lane & 3) * 8;
  const int qa = wave*2;
  const unsigned short* ga0 = xb + (size_t)(m0 + qa*16 + srow)*IN_DIM + scol;
  const unsigned short* gb0 = wb + (size_t)(n0 + qa*16 + srow)*IN_DIM + scol;

  const int l15 = lane & 15, quad = lane >> 4;
  const int arow = wm*64 + l15;
  const int brow = wn*64 + l15;
  const int cs   = (quad ^ ((l15 >> 1) & 3)) << 3;   // swizzled K-granule offset

  // prologue: T0 -> buf0, T1 -> buf1 (4 loads per wave per tile)
  #pragma unroll
  for (int t=0;t<2;++t) {
    unsigned short* buf = smem + t*8192;
    async16(ga0 + t*32,             buf + qa*512);
    async16(ga0 + t*32 + 16*IN_DIM, buf + qa*512 + 512);
    async16(gb0 + t*32,             buf + 4096 + qa*512);
    async16(gb0 + t*32 + 16*IN_DIM, buf + 4096 + qa*512 + 512);
  }

  #pragma unroll
  for (int kt = 0; kt < 15; ++kt) {
    // wait: own tile-kt loads done (<=4 outstanding = tile kt+1), all waves
    __builtin_amdgcn_s_waitcnt(3956);   // vmcnt(4), lgkm/exp ignored
    __builtin_amdgcn_s_barrier();
    if (kt < 14) {                      // issue tile kt+2
      unsigned short* buf = smem + ((kt+2)%3)*8192;
      const int ko = (kt+2)*32;
      async16(ga0 + ko,             buf + qa*512);
      async16(ga0 + ko + 16*IN_DIM, buf + qa*512 + 512);
      async16(gb0 + ko,             buf + 4096 + qa*512);
      async16(gb0 + ko + 16*IN_DIM, buf + 4096 + qa*512 + 512);
    }
    const unsigned short* As = smem + (kt%3)*8192;
    const unsigned short* Bs = As + 4096;
    bf16x8 af[4], bfr[4];
    #pragma unroll
    for (int mi=0;mi<4;++mi)
      af[mi] = *(const bf16x8*)(As + (arow + mi*16)*32 + cs);
    #pragma unroll
    for (int ni=0;ni<4;++ni)
      bfr[ni] = *(const bf16x8*)(Bs + (brow + ni*16)*32 + cs);
    #pragma unroll
    for (int mi=0;mi<4;++mi)
      #pragma unroll
      for (int ni=0;ni<4;++ni)
        acc[mi][ni] = __builtin_amdgcn_mfma_f32_16x16x32_bf16(
            af[mi], bfr[ni], acc[mi][ni], 0, 0, 0);
  }
  // peeled tile 15 (buf 0): full drain
  {
    __builtin_amdgcn_s_waitcnt(3952);   // vmcnt(0)
    __builtin_amdgcn_s_barrier();
    const unsigned short* As = smem;    // 15%3 == 0
    const unsigned short* Bs = As + 4096;
    bf16x8 af[4], bfr[4];
    #pragma unroll
    for (int mi=0;mi<4;++mi)
      af[mi] = *(const bf16x8*)(As + (arow + mi*16)*32 + cs);
    #pragma unroll
    for (int ni=0;ni<4;++ni)
      bfr[ni] = *(const bf16x8*)(Bs + (brow + ni*16)*32 + cs);
    #pragma unroll
    for (int mi=0;mi<4;++mi)
      #pragma unroll
      for (int ni=0;ni<4;++ni)
        acc[mi][ni] = __builtin_amdgcn_mfma_f32_16x16x32_bf16(
            af[mi], bfr[ni], acc[mi][ni], 0, 0, 0);
  }

  // epilogue: bias + sigmoid -> pt[gcol][grow..grow+3] as one ushort4
  #pragma unroll
  for (int ni=0;ni<4;++ni) {
    int gcol = n0 + wn*64 + ni*16 + l15;
    int tt = gcol >> 5, ii = gcol & 31;
    float bv = (ii < NI) ? bias[tt*NI + ii] : 0.f;
    #pragma unroll
    for (int mi=0;mi<4;++mi) {
      ushort4 s4;
      float v0 = acc[mi][ni][0] + bv, v1 = acc[mi][ni][1] + bv;
      float v2 = acc[mi][ni][2] + bv, v3 = acc[mi][ni][3] + bv;
      s4.x = f2b(1.f/(1.f + __expf(-v0)));
      s4.y = f2b(1.f/(1.f + __expf(-v1)));
      s4.z = f2b(1.f/(1.f + __expf(-v2)));
      s4.w = f2b(1.f/(1.f + __expf(-v3)));
      *(ushort4*)(pt + (size_t)gcol*BATCH + (m0 + wm*64 + mi*16 + quad*4)) = s4;
    }
  }
}

// ---------------------------------------------------------------------------
// route: grid (BATCH/64, NTB). Block: 64 rows (lane = row) x 8 trees
// (wave w -> 2 trees). pt reads are full 128B coalesced lines. Cross-wave
// reduce in LDS -> partial [tb][row][16] to ws.
// ---------------------------------------------------------------------------
__global__ __launch_bounds__(256) void route_kernel(
    const unsigned short* __restrict__ pt, const float* __restrict__ lsm,
    float* __restrict__ part)
{
  __shared__ float red[4*64*17];   // padded stride 17 -> conflict-free
  const int tid  = threadIdx.x;
  const int wave = tid >> 6, lane = tid & 63;
  const int r    = blockIdx.x*64 + lane;
  const int tb   = blockIdx.y;

  float oacc[ODIM];
  #pragma unroll
  for (int o=0;o<ODIM;++o) oacc[o] = 0.f;

  #pragma unroll
  for (int j=0;j<2;++j) {
    const int t = tb*TPB + wave*2 + j;
    const unsigned short* pp = pt + (size_t)t*NL*BATCH + r;
    float v[32];
    float p0 = b2f(pp[0]);
    v[0] = p0; v[1] = 1.f - p0;
    #pragma unroll
    for (int d=1; d<=4; ++d) {
      const int s = 1 << d;
      #pragma unroll
      for (int jj=s-1; jj>=0; --jj) {
        float pj = b2f(pp[(size_t)((s-1)+jj)*BATCH]);
        float base = v[jj];
        v[2*jj]   = base * pj;
        v[2*jj+1] = base * (1.f - pj);
      }
    }
    const float* lp = lsm + (size_t)t*NL*ODIM;
    #pragma unroll
    for (int l=0;l<NL;++l) {
      float rr = v[l];
      const float4* c4 = (const float4*)(lp + l*ODIM);
      #pragma unroll
      for (int oq=0;oq<4;++oq) {
        float4 c = c4[oq];
        oacc[oq*4+0] += rr*c.x; oacc[oq*4+1] += rr*c.y;
        oacc[oq*4+2] += rr*c.z; oacc[oq*4+3] += rr*c.w;
      }
    }
  }
  #pragma unroll
  for (int o=0;o<ODIM;++o) red[(wave*64 + lane)*17 + o] = oacc[o];
  __syncthreads();

  const int row = tid >> 2, oq = tid & 3;
  float s0[4];
  #pragma unroll
  for (int k=0;k<4;++k)
    s0[k] = red[(0*64+row)*17 + oq*4 + k] + red[(1*64+row)*17 + oq*4 + k]
          + red[(2*64+row)*17 + oq*4 + k] + red[(3*64+row)*17 + oq*4 + k];
  float4 o4; o4.x=s0[0]; o4.y=s0[1]; o4.z=s0[2]; o4.w=s0[3];
  *(float4*)(part + ((size_t)tb*BATCH + blockIdx.x*64 + row)*ODIM + oq*4) = o4;
}

// ---------------------------------------------------------------------------
// reduce: out[row][o] = sum over NTB tree-block partials
// ---------------------------------------------------------------------------
__global__ __launch_bounds__(256) void reduce_kernel(
    const float* __restrict__ part, float* __restrict__ out)
{
  int gid = blockIdx.x*256 + threadIdx.x;   // 32768 float4 tasks
  const float4* p4 = (const float4*)part;
  float4 s = p4[gid];
  #pragma unroll
  for (int tb=1; tb<NTB; ++tb) {
    float4 v = p4[(size_t)tb*(BATCH*ODIM/4) + gid];
    s.x+=v.x; s.y+=v.y; s.z+=v.z; s.w+=v.w;
  }
  ((float4*)out)[gid] = s;
}

// ---------------------------------------------------------------------------
extern "C" void kernel_launch(void* const* d_in, const int* in_sizes, int n_in,
                              void* d_out, int out_size, void* d_ws, size_t ws_size,
                              hipStream_t stream) {
  const float* x     = (const float*)d_in[0];
  const float* W     = (const float*)d_in[1];
  const float* b     = (const float*)d_in[2];
  const float* leafs = (const float*)d_in[3];
  float* out = (float*)d_out;

  char* ws = (char*)d_ws;
  unsigned short* xb  = (unsigned short*)ws;                       // 8,388,608 B
  unsigned short* wb  = (unsigned short*)(ws + 8388608);           // 2,097,152 B
  float*          lsm = (float*)(ws + 10485760);                   //   131,072 B
  unsigned short* pt  = (unsigned short*)(ws + 10616832);          // 33,554,432 B
  float*          part= (float*)(ws + 44171264);                   //  4,194,304 B

  const int total = BATCH*(IN_DIM/8) + NPAD*(IN_DIM/8) + NT*NL;    // 657408
  prep_kernel<<<dim3((total + 255)/256), dim3(256), 0, stream>>>(
      x, W, leafs, xb, wb, lsm);
  gemm_kernel<<<dim3(BATCH/128, NPAD/128), dim3(256), 0, stream>>>(
      xb, wb, b, pt);
  route_kernel<<<dim3(BATCH/64, NTB), dim3(256), 0, stream>>>(pt, lsm, part);
  reduce_kernel<<<dim3(BATCH*ODIM/4/256), dim3(256), 0, stream>>>(part, out);
}

// Round 6
// 137.314 us; speedup vs baseline: 1.7131x; 1.0159x over previous
//
#include <hip/hip_runtime.h>

#define BATCH 8192
#define IN_DIM 512
#define NT 64
#define NI 31
#define NL 32
#define ODIM 16
#define NPAD (NT*NL)   // 2048 padded GEMM columns
#define NTB 8          // tree-blocks in route split
#define TPB 8          // trees per route block

typedef __attribute__((ext_vector_type(8))) short bf16x8;
typedef __attribute__((ext_vector_type(4))) float f32x4;

__device__ __forceinline__ unsigned short f2b(float f) {
  union { float f; unsigned int u; } v; v.f = f;
  unsigned int r = v.u + 0x7fffu + ((v.u >> 16) & 1u);   // RNE
  return (unsigned short)(r >> 16);
}
__device__ __forceinline__ float b2f(unsigned short h) {
  union { unsigned int u; float f; } v; v.u = ((unsigned int)h) << 16;
  return v.f;
}

// ---------------------------------------------------------------------------
// prep: x,W fp32 -> bf16 with 16B-granule XOR swizzle (slot g of each 32-K
// window holds source granule g ^ ((row>>1)&3)) so the GEMM's LDS reads are
// bank-conflict-free; W padded to 32 cols/tree; leaf softmax * (1/NT).
// ---------------------------------------------------------------------------
__global__ __launch_bounds__(256) void prep_kernel(
    const float* __restrict__ x, const float* __restrict__ W,
    const float* __restrict__ leafs,
    unsigned short* __restrict__ xb, unsigned short* __restrict__ wb,
    float* __restrict__ lsm)
{
  const int NXg = BATCH * (IN_DIM/8);   // 524288 granules of 8
  const int NWg = NPAD  * (IN_DIM/8);   // 131072 granules
  const int NS  = NT*NL;                // 2048 leaf rows
  int gid = blockIdx.x*256 + threadIdx.x;
  if (gid < NXg) {
    int row = gid >> 6, k8 = gid & 63;
    int kt = k8 >> 2, g = k8 & 3;
    int gs = g ^ ((row >> 1) & 3);
    const float* s = x + (size_t)row*IN_DIM + kt*32 + gs*8;
    float4 v0 = ((const float4*)s)[0], v1 = ((const float4*)s)[1];
    ushort4 o0, o1;
    o0.x=f2b(v0.x); o0.y=f2b(v0.y); o0.z=f2b(v0.z); o0.w=f2b(v0.w);
    o1.x=f2b(v1.x); o1.y=f2b(v1.y); o1.z=f2b(v1.z); o1.w=f2b(v1.w);
    ((ushort4*)xb)[gid*2]   = o0;
    ((ushort4*)xb)[gid*2+1] = o1;
  } else if ((gid -= NXg) < NWg) {
    int row = gid >> 6, k8 = gid & 63;
    int t = row >> 5, i = row & 31;
    int kt = k8 >> 2, g = k8 & 3;
    int gs = g ^ ((row >> 1) & 3);
    ushort4 o0, o1;
    if (i == 31) { o0.x=o0.y=o0.z=o0.w=0; o1=o0; }
    else {
      const float* s = W + (size_t)(t*NI+i)*IN_DIM + kt*32 + gs*8;
      float4 v0 = ((const float4*)s)[0], v1 = ((const float4*)s)[1];
      o0.x=f2b(v0.x); o0.y=f2b(v0.y); o0.z=f2b(v0.z); o0.w=f2b(v0.w);
      o1.x=f2b(v1.x); o1.y=f2b(v1.y); o1.z=f2b(v1.z); o1.w=f2b(v1.w);
    }
    ((ushort4*)wb)[gid*2]   = o0;
    ((ushort4*)wb)[gid*2+1] = o1;
  } else if ((gid -= NWg) < NS) {
    const float* src = leafs + (size_t)gid*ODIM;
    float m = src[0];
    #pragma unroll
    for (int o=1;o<ODIM;++o) m = fmaxf(m, src[o]);
    float e[ODIM]; float s = 0.f;
    #pragma unroll
    for (int o=0;o<ODIM;++o) { e[o] = __expf(src[o]-m); s += e[o]; }
    float inv = 1.f/(s*(float)NT);
    #pragma unroll
    for (int o=0;o<ODIM;++o) lsm[(size_t)gid*ODIM+o] = e[o]*inv;
  }
}

// ---------------------------------------------------------------------------
// gemm: bf16 (M=8192,N=2048,K=512), TILE 256x128, BK=32, 4 waves, wave-tile
// 128x64 (8x4 MFMA frags). 2-stage dbuf (48 KB LDS), prefetch issued right
// after __syncthreads so the load has a full compute phase in flight.
// XCD-swizzled block mapping: XCD (bid&7) covers a 1024-row A strip (1 MB)
// + whole B (2 MB) = 3 MB <= 4 MB per-XCD L2.
// Epilogue: bias+sigmoid, transposed store into pt[col][row] bf16.
// ---------------------------------------------------------------------------
__device__ __forceinline__ void async16(const unsigned short* g, unsigned short* l) {
  __builtin_amdgcn_global_load_lds(
      (const __attribute__((address_space(1))) unsigned int*)g,
      (__attribute__((address_space(3))) unsigned int*)l,
      16, 0, 0);
}

#define STG 12288   // shorts per stage: A 256*32=8192 + B 128*32=4096

__global__ __launch_bounds__(256, 2) void gemm_kernel(
    const unsigned short* __restrict__ xb, const unsigned short* __restrict__ wb,
    const float* __restrict__ bias, unsigned short* __restrict__ pt)
{
  __shared__ __align__(16) unsigned short smem[2*STG];   // 49152 B

  const int tid  = threadIdx.x;
  const int lane = tid & 63;
  const int wave = tid >> 6;
  const int wm = wave & 1, wn = wave >> 1;   // wave-tile: M 128, N 64

  // XCD-aware block swizzle: bid&7 selects XCD-strip
  const int bid = blockIdx.x;
  const int m_t = (bid & 7)*4 + (bid >> 7);      // 0..31
  const int n_t = (bid >> 3) & 15;               // 0..15
  const int m0 = m_t * 256, n0 = n_t * 128;

  f32x4 acc[8][4];
  #pragma unroll
  for (int i=0;i<8;++i)
    #pragma unroll
    for (int j=0;j<4;++j) { f32x4 z = {0.f,0.f,0.f,0.f}; acc[i][j] = z; }

  const int srow = lane >> 2, scol = (lane & 3) * 8;
  // wave w stages A chunks 4w..4w+3 (16 rows each), B chunks 2w..2w+1
  const unsigned short* gaw = xb + (size_t)(m0 + wave*64 + srow)*IN_DIM + scol;
  const unsigned short* gbw = wb + (size_t)(n0 + wave*32 + srow)*IN_DIM + scol;

  const int l15 = lane & 15, quad = lane >> 4;
  const int cs   = (quad ^ ((l15 >> 1) & 3)) << 3;   // swizzled K-granule offset

  // prologue: tile 0 into stage 0
  #pragma unroll
  for (int c=0;c<4;++c) async16(gaw + c*16*IN_DIM, smem + wave*2048 + c*512);
  #pragma unroll
  for (int c=0;c<2;++c) async16(gbw + c*16*IN_DIM, smem + 8192 + wave*1024 + c*512);

  for (int kt = 0; kt < 16; ++kt) {
    __syncthreads();                       // drains tile-kt loads + prior reads
    const int cur = (kt & 1) * STG;
    if (kt < 15) {                         // prefetch kt+1 into other stage
      const int nxt = ((kt + 1) & 1) * STG;
      const int ko = (kt + 1) * 32;
      #pragma unroll
      for (int c=0;c<4;++c)
        async16(gaw + ko + c*16*IN_DIM, smem + nxt + wave*2048 + c*512);
      #pragma unroll
      for (int c=0;c<2;++c)
        async16(gbw + ko + c*16*IN_DIM, smem + nxt + 8192 + wave*1024 + c*512);
    }
    const unsigned short* As = smem + cur;
    const unsigned short* Bs = smem + cur + 8192;
    bf16x8 af[8], bfr[4];
    #pragma unroll
    for (int mi=0;mi<8;++mi)
      af[mi] = *(const bf16x8*)(As + (wm*128 + mi*16 + l15)*32 + cs);
    #pragma unroll
    for (int ni=0;ni<4;++ni)
      bfr[ni] = *(const bf16x8*)(Bs + (wn*64 + ni*16 + l15)*32 + cs);
    #pragma unroll
    for (int mi=0;mi<8;++mi)
      #pragma unroll
      for (int ni=0;ni<4;++ni)
        acc[mi][ni] = __builtin_amdgcn_mfma_f32_16x16x32_bf16(
            af[mi], bfr[ni], acc[mi][ni], 0, 0, 0);
  }

  // epilogue: bias + sigmoid -> pt[gcol][grow..grow+3] as one ushort4
  #pragma unroll
  for (int ni=0;ni<4;++ni) {
    int gcol = n0 + wn*64 + ni*16 + l15;
    int tt = gcol >> 5, ii = gcol & 31;
    float bv = (ii < NI) ? bias[tt*NI + ii] : 0.f;
    #pragma unroll
    for (int mi=0;mi<8;++mi) {
      ushort4 s4;
      float v0 = acc[mi][ni][0] + bv, v1 = acc[mi][ni][1] + bv;
      float v2 = acc[mi][ni][2] + bv, v3 = acc[mi][ni][3] + bv;
      s4.x = f2b(1.f/(1.f + __expf(-v0)));
      s4.y = f2b(1.f/(1.f + __expf(-v1)));
      s4.z = f2b(1.f/(1.f + __expf(-v2)));
      s4.w = f2b(1.f/(1.f + __expf(-v3)));
      *(ushort4*)(pt + (size_t)gcol*BATCH + (m0 + wm*128 + mi*16 + quad*4)) = s4;
    }
  }
}

// ---------------------------------------------------------------------------
// route: grid (BATCH/64, NTB). Block: 64 rows (lane = row) x 8 trees
// (wave w -> 2 trees). pt reads are full 128B coalesced lines. Cross-wave
// reduce in LDS -> partial [tb][row][16] to ws.
// ---------------------------------------------------------------------------
__global__ __launch_bounds__(256) void route_kernel(
    const unsigned short* __restrict__ pt, const float* __restrict__ lsm,
    float* __restrict__ part)
{
  __shared__ float red[4*64*17];   // padded stride 17 -> conflict-free
  const int tid  = threadIdx.x;
  const int wave = tid >> 6, lane = tid & 63;
  const int r    = blockIdx.x*64 + lane;
  const int tb   = blockIdx.y;

  float oacc[ODIM];
  #pragma unroll
  for (int o=0;o<ODIM;++o) oacc[o] = 0.f;

  #pragma unroll
  for (int j=0;j<2;++j) {
    const int t = tb*TPB + wave*2 + j;
    const unsigned short* pp = pt + (size_t)t*NL*BATCH + r;
    float v[32];
    float p0 = b2f(pp[0]);
    v[0] = p0; v[1] = 1.f - p0;
    #pragma unroll
    for (int d=1; d<=4; ++d) {
      const int s = 1 << d;
      #pragma unroll
      for (int jj=s-1; jj>=0; --jj) {
        float pj = b2f(pp[(size_t)((s-1)+jj)*BATCH]);
        float base = v[jj];
        v[2*jj]   = base * pj;
        v[2*jj+1] = base * (1.f - pj);
      }
    }
    const float* lp = lsm + (size_t)t*NL*ODIM;
    #pragma unroll
    for (int l=0;l<NL;++l) {
      float rr = v[l];
      const float4* c4 = (const float4*)(lp + l*ODIM);
      #pragma unroll
      for (int oq=0;oq<4;++oq) {
        float4 c = c4[oq];
        oacc[oq*4+0] += rr*c.x; oacc[oq*4+1] += rr*c.y;
        oacc[oq*4+2] += rr*c.z; oacc[oq*4+3] += rr*c.w;
      }
    }
  }
  #pragma unroll
  for (int o=0;o<ODIM;++o) red[(wave*64 + lane)*17 + o] = oacc[o];
  __syncthreads();

  const int row = tid >> 2, oq = tid & 3;
  float s0[4];
  #pragma unroll
  for (int k=0;k<4;++k)
    s0[k] = red[(0*64+row)*17 + oq*4 + k] + red[(1*64+row)*17 + oq*4 + k]
          + red[(2*64+row)*17 + oq*4 + k] + red[(3*64+row)*17 + oq*4 + k];
  float4 o4; o4.x=s0[0]; o4.y=s0[1]; o4.z=s0[2]; o4.w=s0[3];
  *(float4*)(part + ((size_t)tb*BATCH + blockIdx.x*64 + row)*ODIM + oq*4) = o4;
}

// ---------------------------------------------------------------------------
// reduce: out[row][o] = sum over NTB tree-block partials
// ---------------------------------------------------------------------------
__global__ __launch_bounds__(256) void reduce_kernel(
    const float* __restrict__ part, float* __restrict__ out)
{
  int gid = blockIdx.x*256 + threadIdx.x;   // 32768 float4 tasks
  const float4* p4 = (const float4*)part;
  float4 s = p4[gid];
  #pragma unroll
  for (int tb=1; tb<NTB; ++tb) {
    float4 v = p4[(size_t)tb*(BATCH*ODIM/4) + gid];
    s.x+=v.x; s.y+=v.y; s.z+=v.z; s.w+=v.w;
  }
  ((float4*)out)[gid] = s;
}

// ---------------------------------------------------------------------------
extern "C" void kernel_launch(void* const* d_in, const int* in_sizes, int n_in,
                              void* d_out, int out_size, void* d_ws, size_t ws_size,
                              hipStream_t stream) {
  const float* x     = (const float*)d_in[0];
  const float* W     = (const float*)d_in[1];
  const float* b     = (const float*)d_in[2];
  const float* leafs = (const float*)d_in[3];
  float* out = (float*)d_out;

  char* ws = (char*)d_ws;
  unsigned short* xb  = (unsigned short*)ws;                       // 8,388,608 B
  unsigned short* wb  = (unsigned short*)(ws + 8388608);           // 2,097,152 B
  float*          lsm = (float*)(ws + 10485760);                   //   131,072 B
  unsigned short* pt  = (unsigned short*)(ws + 10616832);          // 33,554,432 B
  float*          part= (float*)(ws + 44171264);                   //  4,194,304 B

  const int total = BATCH*(IN_DIM/8) + NPAD*(IN_DIM/8) + NT*NL;    // 657408
  prep_kernel<<<dim3((total + 255)/256), dim3(256), 0, stream>>>(
      x, W, leafs, xb, wb, lsm);
  gemm_kernel<<<dim3(512), dim3(256), 0, stream>>>(
      xb, wb, b, pt);
  route_kernel<<<dim3(BATCH/64, NTB), dim3(256), 0, stream>>>(pt, lsm, part);
  reduce_kernel<<<dim3(BATCH*ODIM/4/256), dim3(256), 0, stream>>>(part, out);
}

// Round 7
// 109.740 us; speedup vs baseline: 2.1435x; 1.2513x over previous
//
#include <hip/hip_runtime.h>

#define BATCH 8192
#define IN_DIM 512
#define NT 64
#define NI 31
#define NL 32
#define ODIM 16
#define NPAD (NT*NL)   // 2048 padded GEMM columns
#define NCB 16         // column blocks (2048/128)

typedef __attribute__((ext_vector_type(8))) short bf16x8;
typedef __attribute__((ext_vector_type(4))) float f32x4;

__device__ __forceinline__ unsigned short f2b(float f) {
  union { float f; unsigned int u; } v; v.f = f;
  unsigned int r = v.u + 0x7fffu + ((v.u >> 16) & 1u);   // RNE
  return (unsigned short)(r >> 16);
}
__device__ __forceinline__ float b2f(unsigned short h) {
  union { unsigned int u; float f; } v; v.u = ((unsigned int)h) << 16;
  return v.f;
}

// ---------------------------------------------------------------------------
// prep: x,W fp32 -> bf16 with 16B-granule XOR swizzle (slot g of each 32-K
// window holds source granule g ^ ((row>>1)&3)) so the GEMM's LDS reads are
// bank-conflict-free; W padded to 32 cols/tree; leaf softmax * (1/NT).
// ---------------------------------------------------------------------------
__global__ __launch_bounds__(256) void prep_kernel(
    const float* __restrict__ x, const float* __restrict__ W,
    const float* __restrict__ leafs,
    unsigned short* __restrict__ xb, unsigned short* __restrict__ wb,
    float* __restrict__ lsm)
{
  const int NXg = BATCH * (IN_DIM/8);   // 524288 granules of 8
  const int NWg = NPAD  * (IN_DIM/8);   // 131072 granules
  const int NS  = NT*NL;                // 2048 leaf rows
  int gid = blockIdx.x*256 + threadIdx.x;
  if (gid < NXg) {
    int row = gid >> 6, k8 = gid & 63;
    int kt = k8 >> 2, g = k8 & 3;
    int gs = g ^ ((row >> 1) & 3);
    const float* s = x + (size_t)row*IN_DIM + kt*32 + gs*8;
    float4 v0 = ((const float4*)s)[0], v1 = ((const float4*)s)[1];
    ushort4 o0, o1;
    o0.x=f2b(v0.x); o0.y=f2b(v0.y); o0.z=f2b(v0.z); o0.w=f2b(v0.w);
    o1.x=f2b(v1.x); o1.y=f2b(v1.y); o1.z=f2b(v1.z); o1.w=f2b(v1.w);
    ((ushort4*)xb)[gid*2]   = o0;
    ((ushort4*)xb)[gid*2+1] = o1;
  } else if ((gid -= NXg) < NWg) {
    int row = gid >> 6, k8 = gid & 63;
    int t = row >> 5, i = row & 31;
    int kt = k8 >> 2, g = k8 & 3;
    int gs = g ^ ((row >> 1) & 3);
    ushort4 o0, o1;
    if (i == 31) { o0.x=o0.y=o0.z=o0.w=0; o1=o0; }
    else {
      const float* s = W + (size_t)(t*NI+i)*IN_DIM + kt*32 + gs*8;
      float4 v0 = ((const float4*)s)[0], v1 = ((const float4*)s)[1];
      o0.x=f2b(v0.x); o0.y=f2b(v0.y); o0.z=f2b(v0.z); o0.w=f2b(v0.w);
      o1.x=f2b(v1.x); o1.y=f2b(v1.y); o1.z=f2b(v1.z); o1.w=f2b(v1.w);
    }
    ((ushort4*)wb)[gid*2]   = o0;
    ((ushort4*)wb)[gid*2+1] = o1;
  } else if ((gid -= NWg) < NS) {
    const float* src = leafs + (size_t)gid*ODIM;
    float m = src[0];
    #pragma unroll
    for (int o=1;o<ODIM;++o) m = fmaxf(m, src[o]);
    float e[ODIM]; float s = 0.f;
    #pragma unroll
    for (int o=0;o<ODIM;++o) { e[o] = __expf(src[o]-m); s += e[o]; }
    float inv = 1.f/(s*(float)NT);
    #pragma unroll
    for (int o=0;o<ODIM;++o) lsm[(size_t)gid*ODIM+o] = e[o]*inv;
  }
}

// ---------------------------------------------------------------------------
// fused: bf16 GEMM (M=8192,N=2048,K=512) tile 256x128 + sigmoid + route
// products + leaf mix, all in one kernel. 4 waves, wave-tile 128x64.
// 2-stage dbuf staging (48 KB) overlaid by Pt[256][130] bf16 (66.5 KB) in
// the epilogue; lsm slice for the block's 4 trees lives at +66560 B (8 KB).
// Partials per colblock -> ws (plain stores), summed by reduce_kernel.
// ---------------------------------------------------------------------------
__device__ __forceinline__ void async16(const unsigned short* g, unsigned short* l) {
  __builtin_amdgcn_global_load_lds(
      (const __attribute__((address_space(1))) unsigned int*)g,
      (__attribute__((address_space(3))) unsigned int*)l,
      16, 0, 0);
}

#define STG 12288          // shorts per stage: A 256*32=8192 + B 128*32=4096
#define LSM_OFF 66560      // byte offset of lsm LDS slice (after Pt 256*130*2)

__global__ __launch_bounds__(256, 2) void fused_kernel(
    const unsigned short* __restrict__ xb, const unsigned short* __restrict__ wb,
    const float* __restrict__ bias, const float* __restrict__ lsm,
    float* __restrict__ part)
{
  __shared__ __align__(16) unsigned char smem_raw[74752];
  unsigned short* smem = (unsigned short*)smem_raw;        // staging / Pt
  float* lsmL = (float*)(smem_raw + LSM_OFF);              // [4][32][16]

  const int tid  = threadIdx.x;
  const int lane = tid & 63;
  const int wave = tid >> 6;
  const int wm = wave & 1, wn = wave >> 1;   // wave-tile: M 128, N 64

  // XCD-aware block swizzle: bid&7 selects XCD-strip (1 MB A + 2 MB B in L2)
  const int bid = blockIdx.x;
  const int m_t = (bid & 7)*4 + (bid >> 7);      // 0..31
  const int n_t = (bid >> 3) & 15;               // 0..15
  const int m0 = m_t * 256, n0 = n_t * 128;

  f32x4 acc[8][4];
  #pragma unroll
  for (int i=0;i<8;++i)
    #pragma unroll
    for (int j=0;j<4;++j) { f32x4 z = {0.f,0.f,0.f,0.f}; acc[i][j] = z; }

  const int srow = lane >> 2, scol = (lane & 3) * 8;
  const unsigned short* gaw = xb + (size_t)(m0 + wave*64 + srow)*IN_DIM + scol;
  const unsigned short* gbw = wb + (size_t)(n0 + wave*32 + srow)*IN_DIM + scol;

  const int l15 = lane & 15, quad = lane >> 4;
  const int cs   = (quad ^ ((l15 >> 1) & 3)) << 3;   // swizzled K-granule offset

  // prologue: tile 0 into stage 0
  #pragma unroll
  for (int c=0;c<4;++c) async16(gaw + c*16*IN_DIM, smem + wave*2048 + c*512);
  #pragma unroll
  for (int c=0;c<2;++c) async16(gbw + c*16*IN_DIM, smem + 8192 + wave*1024 + c*512);

  for (int kt = 0; kt < 16; ++kt) {
    __syncthreads();                       // drains tile-kt loads + prior reads
    const int cur = (kt & 1) * STG;
    if (kt < 15) {                         // prefetch kt+1 into other stage
      const int nxt = ((kt + 1) & 1) * STG;
      const int ko = (kt + 1) * 32;
      #pragma unroll
      for (int c=0;c<4;++c)
        async16(gaw + ko + c*16*IN_DIM, smem + nxt + wave*2048 + c*512);
      #pragma unroll
      for (int c=0;c<2;++c)
        async16(gbw + ko + c*16*IN_DIM, smem + nxt + 8192 + wave*1024 + c*512);
    }
    const unsigned short* As = smem + cur;
    const unsigned short* Bs = smem + cur + 8192;
    bf16x8 af[8], bfr[4];
    #pragma unroll
    for (int mi=0;mi<8;++mi)
      af[mi] = *(const bf16x8*)(As + (wm*128 + mi*16 + l15)*32 + cs);
    #pragma unroll
    for (int ni=0;ni<4;++ni)
      bfr[ni] = *(const bf16x8*)(Bs + (wn*64 + ni*16 + l15)*32 + cs);
    #pragma unroll
    for (int mi=0;mi<8;++mi)
      #pragma unroll
      for (int ni=0;ni<4;++ni)
        acc[mi][ni] = __builtin_amdgcn_mfma_f32_16x16x32_bf16(
            af[mi], bfr[ni], acc[mi][ni], 0, 0, 0);
  }

  // lsm slice for this block's 4 trees: 2048 floats, coalesced global load
  const float4* lsm4 = (const float4*)(lsm + (size_t)(n_t*4)*(NL*ODIM));
  float4 lv0 = lsm4[tid], lv1 = lsm4[tid + 256];

  __syncthreads();   // all staging ds_reads done before Pt overlays staging

  ((float4*)lsmL)[tid]       = lv0;
  ((float4*)lsmL)[tid + 256] = lv1;

  // epilogue 1: bias + sigmoid -> Pt[256][130] bf16 (stride 130: 2-way banks)
  unsigned short* Pt = smem;
  #pragma unroll
  for (int ni=0;ni<4;++ni) {
    int cl = wn*64 + ni*16 + l15;          // local col 0..127
    int gcol = n0 + cl;
    int tt = gcol >> 5, ii = gcol & 31;
    float bv = (ii < NI) ? bias[tt*NI + ii] : 0.f;
    #pragma unroll
    for (int mi=0;mi<8;++mi) {
      int lrow = wm*128 + mi*16 + quad*4;
      #pragma unroll
      for (int r=0;r<4;++r) {
        float v = acc[mi][ni][r] + bv;
        Pt[(lrow + r)*130 + cl] = f2b(1.f/(1.f + __expf(-v)));
      }
    }
  }
  __syncthreads();

  // epilogue 2: route expansion + leaf mix; thread = row (256 rows), 4 trees
  const int row = tid;
  float oacc[ODIM];
  #pragma unroll
  for (int o=0;o<ODIM;++o) oacc[o] = 0.f;

  #pragma unroll
  for (int tl=0; tl<4; ++tl) {
    const unsigned short* pr = Pt + row*130 + tl*32;
    float v[32];
    float p0 = b2f(pr[0]);
    v[0] = p0; v[1] = 1.f - p0;
    #pragma unroll
    for (int d=1; d<=4; ++d) {
      const int s = 1 << d;
      #pragma unroll
      for (int j=s-1; j>=0; --j) {
        float pj = b2f(pr[(s-1)+j]);
        float base = v[j];
        v[2*j]   = base * pj;
        v[2*j+1] = base * (1.f - pj);
      }
    }
    const float* lp = lsmL + tl*(NL*ODIM);
    #pragma unroll
    for (int l=0;l<NL;++l) {
      float rr = v[l];
      const float4* c4 = (const float4*)(lp + l*ODIM);
      #pragma unroll
      for (int oq=0;oq<4;++oq) {
        float4 c = c4[oq];
        oacc[oq*4+0] += rr*c.x; oacc[oq*4+1] += rr*c.y;
        oacc[oq*4+2] += rr*c.z; oacc[oq*4+3] += rr*c.w;
      }
    }
  }

  // partial[n_t][m0+row][16]; each thread writes its row's full 64 B line
  float* op = part + ((size_t)n_t*BATCH + (m0 + row))*ODIM;
  #pragma unroll
  for (int oq=0;oq<4;++oq) {
    float4 v; v.x=oacc[oq*4+0]; v.y=oacc[oq*4+1];
    v.z=oacc[oq*4+2]; v.w=oacc[oq*4+3];
    ((float4*)op)[oq] = v;
  }
}

// ---------------------------------------------------------------------------
// reduce: out[row][o] = sum over 16 colblock partials
// ---------------------------------------------------------------------------
__global__ __launch_bounds__(256) void reduce_kernel(
    const float* __restrict__ part, float* __restrict__ out)
{
  int gid = blockIdx.x*256 + threadIdx.x;   // 32768 float4 tasks
  const float4* p4 = (const float4*)part;
  float4 s = p4[gid];
  #pragma unroll
  for (int cb=1; cb<NCB; ++cb) {
    float4 v = p4[(size_t)cb*(BATCH*ODIM/4) + gid];
    s.x+=v.x; s.y+=v.y; s.z+=v.z; s.w+=v.w;
  }
  ((float4*)out)[gid] = s;
}

// ---------------------------------------------------------------------------
extern "C" void kernel_launch(void* const* d_in, const int* in_sizes, int n_in,
                              void* d_out, int out_size, void* d_ws, size_t ws_size,
                              hipStream_t stream) {
  const float* x     = (const float*)d_in[0];
  const float* W     = (const float*)d_in[1];
  const float* b     = (const float*)d_in[2];
  const float* leafs = (const float*)d_in[3];
  float* out = (float*)d_out;

  char* ws = (char*)d_ws;
  unsigned short* xb  = (unsigned short*)ws;                       // 8,388,608 B
  unsigned short* wb  = (unsigned short*)(ws + 8388608);           // 2,097,152 B
  float*          lsm = (float*)(ws + 10485760);                   //   131,072 B
  float*          part= (float*)(ws + 10616832);                   // 8,388,608 B

  const int total = BATCH*(IN_DIM/8) + NPAD*(IN_DIM/8) + NT*NL;    // 657408
  prep_kernel<<<dim3((total + 255)/256), dim3(256), 0, stream>>>(
      x, W, leafs, xb, wb, lsm);
  fused_kernel<<<dim3(512), dim3(256), 0, stream>>>(
      xb, wb, b, lsm, part);
  reduce_kernel<<<dim3(BATCH*ODIM/4/256), dim3(256), 0, stream>>>(part, out);
}

// Round 8
// 104.680 us; speedup vs baseline: 2.2471x; 1.0483x over previous
//
#include <hip/hip_runtime.h>

#define BATCH 8192
#define IN_DIM 512
#define NT 64
#define NI 31
#define NL 32
#define ODIM 16
#define NPAD (NT*NL)   // 2048 padded GEMM columns
#define NCB 16         // column blocks (2048/128)

typedef __attribute__((ext_vector_type(8))) short bf16x8;
typedef __attribute__((ext_vector_type(4))) float f32x4;

__device__ __forceinline__ unsigned short f2b(float f) {
  union { float f; unsigned int u; } v; v.f = f;
  unsigned int r = v.u + 0x7fffu + ((v.u >> 16) & 1u);   // RNE
  return (unsigned short)(r >> 16);
}
__device__ __forceinline__ float b2f(unsigned short h) {
  union { unsigned int u; float f; } v; v.u = ((unsigned int)h) << 16;
  return v.f;
}

// ---------------------------------------------------------------------------
// prep: x,W fp32 -> bf16 with 16B-granule XOR swizzle (slot g of each 32-K
// window holds source granule g ^ ((row>>1)&3)) so the GEMM's LDS reads are
// bank-conflict-free; W padded to 32 cols/tree; leaf softmax * (1/NT).
// ---------------------------------------------------------------------------
__global__ __launch_bounds__(256) void prep_kernel(
    const float* __restrict__ x, const float* __restrict__ W,
    const float* __restrict__ leafs,
    unsigned short* __restrict__ xb, unsigned short* __restrict__ wb,
    float* __restrict__ lsm)
{
  const int NXg = BATCH * (IN_DIM/8);   // 524288 granules of 8
  const int NWg = NPAD  * (IN_DIM/8);   // 131072 granules
  const int NS  = NT*NL;                // 2048 leaf rows
  int gid = blockIdx.x*256 + threadIdx.x;
  if (gid < NXg) {
    int row = gid >> 6, k8 = gid & 63;
    int kt = k8 >> 2, g = k8 & 3;
    int gs = g ^ ((row >> 1) & 3);
    const float* s = x + (size_t)row*IN_DIM + kt*32 + gs*8;
    float4 v0 = ((const float4*)s)[0], v1 = ((const float4*)s)[1];
    ushort4 o0, o1;
    o0.x=f2b(v0.x); o0.y=f2b(v0.y); o0.z=f2b(v0.z); o0.w=f2b(v0.w);
    o1.x=f2b(v1.x); o1.y=f2b(v1.y); o1.z=f2b(v1.z); o1.w=f2b(v1.w);
    ((ushort4*)xb)[gid*2]   = o0;
    ((ushort4*)xb)[gid*2+1] = o1;
  } else if ((gid -= NXg) < NWg) {
    int row = gid >> 6, k8 = gid & 63;
    int t = row >> 5, i = row & 31;
    int kt = k8 >> 2, g = k8 & 3;
    int gs = g ^ ((row >> 1) & 3);
    ushort4 o0, o1;
    if (i == 31) { o0.x=o0.y=o0.z=o0.w=0; o1=o0; }
    else {
      const float* s = W + (size_t)(t*NI+i)*IN_DIM + kt*32 + gs*8;
      float4 v0 = ((const float4*)s)[0], v1 = ((const float4*)s)[1];
      o0.x=f2b(v0.x); o0.y=f2b(v0.y); o0.z=f2b(v0.z); o0.w=f2b(v0.w);
      o1.x=f2b(v1.x); o1.y=f2b(v1.y); o1.z=f2b(v1.z); o1.w=f2b(v1.w);
    }
    ((ushort4*)wb)[gid*2]   = o0;
    ((ushort4*)wb)[gid*2+1] = o1;
  } else if ((gid -= NWg) < NS) {
    const float* src = leafs + (size_t)gid*ODIM;
    float m = src[0];
    #pragma unroll
    for (int o=1;o<ODIM;++o) m = fmaxf(m, src[o]);
    float e[ODIM]; float s = 0.f;
    #pragma unroll
    for (int o=0;o<ODIM;++o) { e[o] = __expf(src[o]-m); s += e[o]; }
    float inv = 1.f/(s*(float)NT);
    #pragma unroll
    for (int o=0;o<ODIM;++o) lsm[(size_t)gid*ODIM+o] = e[o]*inv;
  }
}

// ---------------------------------------------------------------------------
// fused: bf16 GEMM (M=8192,N=2048,K=512) tile 256x128 + sigmoid + route
// expansion + SECOND MFMA (routes[256x128] @ lsm_slice[128x16]).
// 4 waves, wave-tile 128x64, 2-stage dbuf staging (48 KB).
// Epilogue LDS overlay: Pt[256][130] bf16 (p-values) then Rt[256][136] bf16
// (route A-operand tile, 16B-aligned rows). lsm B-frags live in registers.
// ---------------------------------------------------------------------------
__device__ __forceinline__ void async16(const unsigned short* g, unsigned short* l) {
  __builtin_amdgcn_global_load_lds(
      (const __attribute__((address_space(1))) unsigned int*)g,
      (__attribute__((address_space(3))) unsigned int*)l,
      16, 0, 0);
}

#define STG 12288          // shorts per stage: A 256*32=8192 + B 128*32=4096

__global__ __launch_bounds__(256, 2) void fused_kernel(
    const unsigned short* __restrict__ xb, const unsigned short* __restrict__ wb,
    const float* __restrict__ bias, const float* __restrict__ lsm,
    float* __restrict__ part)
{
  // max(staging 2*12288, Pt 256*130=33280, Rt 256*136=34816) shorts
  __shared__ __align__(16) unsigned short smem[34816];   // 69632 B

  const int tid  = threadIdx.x;
  const int lane = tid & 63;
  const int wave = tid >> 6;
  const int wm = wave & 1, wn = wave >> 1;   // wave-tile: M 128, N 64

  // XCD-aware block swizzle
  const int bid = blockIdx.x;
  const int m_t = (bid & 7)*4 + (bid >> 7);      // 0..31
  const int n_t = (bid >> 3) & 15;               // 0..15
  const int m0 = m_t * 256, n0 = n_t * 128;

  f32x4 acc[8][4];
  #pragma unroll
  for (int i=0;i<8;++i)
    #pragma unroll
    for (int j=0;j<4;++j) { f32x4 z = {0.f,0.f,0.f,0.f}; acc[i][j] = z; }

  const int srow = lane >> 2, scol = (lane & 3) * 8;
  const unsigned short* gaw = xb + (size_t)(m0 + wave*64 + srow)*IN_DIM + scol;
  const unsigned short* gbw = wb + (size_t)(n0 + wave*32 + srow)*IN_DIM + scol;

  const int l15 = lane & 15, quad = lane >> 4;
  const int cs   = (quad ^ ((l15 >> 1) & 3)) << 3;   // swizzled K-granule offset

  // prologue: tile 0 into stage 0
  #pragma unroll
  for (int c=0;c<4;++c) async16(gaw + c*16*IN_DIM, smem + wave*2048 + c*512);
  #pragma unroll
  for (int c=0;c<2;++c) async16(gbw + c*16*IN_DIM, smem + 8192 + wave*1024 + c*512);

  for (int kt = 0; kt < 16; ++kt) {
    __syncthreads();                       // drains tile-kt loads + prior reads
    const int cur = (kt & 1) * STG;
    if (kt < 15) {                         // prefetch kt+1 into other stage
      const int nxt = ((kt + 1) & 1) * STG;
      const int ko = (kt + 1) * 32;
      #pragma unroll
      for (int c=0;c<4;++c)
        async16(gaw + ko + c*16*IN_DIM, smem + nxt + wave*2048 + c*512);
      #pragma unroll
      for (int c=0;c<2;++c)
        async16(gbw + ko + c*16*IN_DIM, smem + nxt + 8192 + wave*1024 + c*512);
    }
    const unsigned short* As = smem + cur;
    const unsigned short* Bs = smem + cur + 8192;
    bf16x8 af[8], bfr[4];
    #pragma unroll
    for (int mi=0;mi<8;++mi)
      af[mi] = *(const bf16x8*)(As + (wm*128 + mi*16 + l15)*32 + cs);
    #pragma unroll
    for (int ni=0;ni<4;++ni)
      bfr[ni] = *(const bf16x8*)(Bs + (wn*64 + ni*16 + l15)*32 + cs);
    #pragma unroll
    for (int mi=0;mi<8;++mi)
      #pragma unroll
      for (int ni=0;ni<4;++ni)
        acc[mi][ni] = __builtin_amdgcn_mfma_f32_16x16x32_bf16(
            af[mi], bfr[ni], acc[mi][ni], 0, 0, 0);
  }

  // lsm B-frags for the second MFMA: lane(l15=n, quad) elem j = bf16 of
  // lsm[(t0+s)*32 + quad*8 + j][n]  (kstep s == tree s of this block)
  bf16x8 bleaf[4];
  {
    const int t0 = n_t * 4;
    #pragma unroll
    for (int s=0;s<4;++s) {
      union { bf16x8 v; unsigned short u[8]; } tmp;
      #pragma unroll
      for (int j=0;j<8;++j)
        tmp.u[j] = f2b(lsm[((size_t)(t0+s)*NL + quad*8 + j)*ODIM + l15]);
      bleaf[s] = tmp.v;
    }
  }

  __syncthreads();   // staging ds_reads done before Pt overlays staging

  // Phase A: bias + sigmoid -> Pt[256][130] bf16
  unsigned short* Pt = smem;
  #pragma unroll
  for (int ni=0;ni<4;++ni) {
    int cl = wn*64 + ni*16 + l15;          // local col 0..127
    int gcol = n0 + cl;
    int tt = gcol >> 5, ii = gcol & 31;
    float bv = (ii < NI) ? bias[tt*NI + ii] : 0.f;
    #pragma unroll
    for (int mi=0;mi<8;++mi) {
      int lrow = wm*128 + mi*16 + quad*4;
      #pragma unroll
      for (int r=0;r<4;++r) {
        float v = acc[mi][ni][r] + bv;
        Pt[(lrow + r)*130 + cl] = f2b(1.f/(1.f + __expf(-v)));
      }
    }
  }
  __syncthreads();

  // Phase B: thread=row expands 4 trees' routes into 64 packed bf16 pairs
  const int row = tid;
  unsigned int rt[64];
  #pragma unroll
  for (int tl=0; tl<4; ++tl) {
    const unsigned short* pr = Pt + row*130 + tl*32;
    float q[31];
    #pragma unroll
    for (int i=0;i<31;++i) q[i] = b2f(pr[i]);
    float v[32];
    v[0] = q[0]; v[1] = 1.f - q[0];
    #pragma unroll
    for (int d=1; d<=4; ++d) {
      const int s = 1 << d;
      #pragma unroll
      for (int j=s-1; j>=0; --j) {
        float pj = q[(s-1)+j];
        float base = v[j];
        v[2*j]   = base * pj;
        v[2*j+1] = base * (1.f - pj);
      }
    }
    #pragma unroll
    for (int k=0;k<16;++k)
      rt[tl*16+k] = (unsigned int)f2b(v[2*k]) | ((unsigned int)f2b(v[2*k+1]) << 16);
  }
  __syncthreads();   // all Pt reads done before Rt overwrites

  // write Rt[256][136] bf16 (rows 272 B, 16B-aligned); own row, 16x b128
  unsigned int* Rt32 = (unsigned int*)smem;
  {
    uint4* dst = (uint4*)(Rt32 + row*68);
    #pragma unroll
    for (int c=0;c<16;++c) {
      uint4 w; w.x=rt[c*4]; w.y=rt[c*4+1]; w.z=rt[c*4+2]; w.w=rt[c*4+3];
      dst[c] = w;
    }
  }
  __syncthreads();

  // second MFMA: routes[256x128] @ lsm[128x16]; wave covers mtiles 4w..4w+3
  const unsigned short* RtS = smem;
  #pragma unroll
  for (int mt=0; mt<4; ++mt) {
    const int mrow = (wave*4 + mt)*16;
    f32x4 a2 = {0.f,0.f,0.f,0.f};
    #pragma unroll
    for (int s=0;s<4;++s) {
      bf16x8 af2 = *(const bf16x8*)(RtS + (mrow + l15)*136 + s*32 + quad*8);
      a2 = __builtin_amdgcn_mfma_f32_16x16x32_bf16(af2, bleaf[s], a2, 0, 0, 0);
    }
    // C/D: col=l15 (ODIM), row=quad*4+r
    float* op = part + ((size_t)n_t*BATCH + (m0 + mrow + quad*4))*ODIM + l15;
    #pragma unroll
    for (int r=0;r<4;++r)
      op[r*ODIM] = a2[r];
  }
}

// ---------------------------------------------------------------------------
// reduce: out[row][o] = sum over 16 colblock partials
// ---------------------------------------------------------------------------
__global__ __launch_bounds__(256) void reduce_kernel(
    const float* __restrict__ part, float* __restrict__ out)
{
  int gid = blockIdx.x*256 + threadIdx.x;   // 32768 float4 tasks
  const float4* p4 = (const float4*)part;
  float4 s = p4[gid];
  #pragma unroll
  for (int cb=1; cb<NCB; ++cb) {
    float4 v = p4[(size_t)cb*(BATCH*ODIM/4) + gid];
    s.x+=v.x; s.y+=v.y; s.z+=v.z; s.w+=v.w;
  }
  ((float4*)out)[gid] = s;
}

// ---------------------------------------------------------------------------
extern "C" void kernel_launch(void* const* d_in, const int* in_sizes, int n_in,
                              void* d_out, int out_size, void* d_ws, size_t ws_size,
                              hipStream_t stream) {
  const float* x     = (const float*)d_in[0];
  const float* W     = (const float*)d_in[1];
  const float* b     = (const float*)d_in[2];
  const float* leafs = (const float*)d_in[3];
  float* out = (float*)d_out;

  char* ws = (char*)d_ws;
  unsigned short* xb  = (unsigned short*)ws;                       // 8,388,608 B
  unsigned short* wb  = (unsigned short*)(ws + 8388608);           // 2,097,152 B
  float*          lsm = (float*)(ws + 10485760);                   //   131,072 B
  float*          part= (float*)(ws + 10616832);                   // 8,388,608 B

  const int total = BATCH*(IN_DIM/8) + NPAD*(IN_DIM/8) + NT*NL;    // 657408
  prep_kernel<<<dim3((total + 255)/256), dim3(256), 0, stream>>>(
      x, W, leafs, xb, wb, lsm);
  fused_kernel<<<dim3(512), dim3(256), 0, stream>>>(
      xb, wb, b, lsm, part);
  reduce_kernel<<<dim3(BATCH*ODIM/4/256), dim3(256), 0, stream>>>(part, out);
}